// Round 2
// baseline (3601.540 us; speedup 1.0000x reference)
//
#include <hip/hip_runtime.h>
#include <math.h>

#define HDIM 512
#define LSEQ 2048
#define NH 8
#define DH 64
#define NEGBIG (-3.0e38f)

// ---------------------------------------------------------------------------
// Generic fp32 tiled GEMM: C[m,c] = act( sum_k A[m,k] * B[k*sk + (c>>6)*shi + (c&63)*slo]
//                                        + bias[c] (+ res[m*512+c]) )
// outmode 0: C[m*512+c]
// outmode 1: qkv layout  ((b*NH+n)*LSEQ+l)*DH+d   with b=m>>11,l=m&2047,n=c>>6,d=c&63
// outmode 2: rel layout  n*(LSEQ*DH) + (LSEQ-1-m)*DH + d
// ---------------------------------------------------------------------------
__global__ __launch_bounds__(256) void gemm_kernel(
    const float* __restrict__ A, const float* __restrict__ B,
    const float* __restrict__ bias, const float* __restrict__ res,
    float* __restrict__ C, int M, int K,
    int sk, int shi, int slo, int outmode, int dogelu)
{
  __shared__ __align__(16) float As[16 * 68];
  __shared__ __align__(16) float Bs[16 * 68];
  const int t = threadIdx.x;
  const int m0 = blockIdx.y * 64, n0 = blockIdx.x * 64;
  const int tx = t & 15, ty = t >> 4;

  float acc[4][4];
  #pragma unroll
  for (int i = 0; i < 4; ++i)
    #pragma unroll
    for (int j = 0; j < 4; ++j) acc[i][j] = 0.0f;

  for (int k0 = 0; k0 < K; k0 += 16) {
    // A tile 64x16, transposed into As[kk][mm]
    {
      int mm = t >> 2, kb = (t & 3) << 2;
      float4 a4 = *(const float4*)(A + (size_t)(m0 + mm) * K + k0 + kb);
      As[(kb + 0) * 68 + mm] = a4.x;
      As[(kb + 1) * 68 + mm] = a4.y;
      As[(kb + 2) * 68 + mm] = a4.z;
      As[(kb + 3) * 68 + mm] = a4.w;
    }
    // B tile 16x64 via generic strides
    {
      int kk = t >> 4, nb = (t & 15) << 2;
      int krow = (k0 + kk) * sk;
      #pragma unroll
      for (int u = 0; u < 4; ++u) {
        int c = n0 + nb + u;
        Bs[kk * 68 + nb + u] = B[krow + (c >> 6) * shi + (c & 63) * slo];
      }
    }
    __syncthreads();
    #pragma unroll
    for (int kk = 0; kk < 16; ++kk) {
      float4 av = *(const float4*)(As + kk * 68 + (ty << 2));
      float4 bv = *(const float4*)(Bs + kk * 68 + (tx << 2));
      acc[0][0] += av.x * bv.x; acc[0][1] += av.x * bv.y; acc[0][2] += av.x * bv.z; acc[0][3] += av.x * bv.w;
      acc[1][0] += av.y * bv.x; acc[1][1] += av.y * bv.y; acc[1][2] += av.y * bv.z; acc[1][3] += av.y * bv.w;
      acc[2][0] += av.z * bv.x; acc[2][1] += av.z * bv.y; acc[2][2] += av.z * bv.z; acc[2][3] += av.z * bv.w;
      acc[3][0] += av.w * bv.x; acc[3][1] += av.w * bv.y; acc[3][2] += av.w * bv.z; acc[3][3] += av.w * bv.w;
    }
    __syncthreads();
  }

  const int cb_ = n0 + (tx << 2);
  float4 bv = *(const float4*)(bias + cb_);
  #pragma unroll
  for (int i = 0; i < 4; ++i) {
    int m = m0 + (ty << 2) + i;
    float vv[4];
    vv[0] = acc[i][0] + bv.x; vv[1] = acc[i][1] + bv.y;
    vv[2] = acc[i][2] + bv.z; vv[3] = acc[i][3] + bv.w;
    if (res) {
      float4 r4 = *(const float4*)(res + (size_t)m * 512 + cb_);
      vv[0] += r4.x; vv[1] += r4.y; vv[2] += r4.z; vv[3] += r4.w;
    }
    if (dogelu) {
      #pragma unroll
      for (int j = 0; j < 4; ++j)
        vv[j] = 0.5f * vv[j] * (1.0f + erff(vv[j] * 0.70710678118654752f));
    }
    float4 o; o.x = vv[0]; o.y = vv[1]; o.z = vv[2]; o.w = vv[3];
    if (outmode == 0) {
      *(float4*)(C + (size_t)m * 512 + cb_) = o;
    } else if (outmode == 1) {
      int b = m >> 11, l = m & 2047, n = cb_ >> 6, d = cb_ & 63;
      *(float4*)(C + (size_t)((b * NH + n) * LSEQ + l) * DH + d) = o;
    } else {
      int n = cb_ >> 6, d = cb_ & 63;
      *(float4*)(C + (size_t)n * (LSEQ * DH) + (size_t)(LSEQ - 1 - m) * DH + d) = o;
    }
  }
}

// ---------------------------------------------------------------------------
// Flash-style causal attention with Transformer-XL relative positions.
// score[i,j] = (qc_i . k_j + qp_i . re[n][i-j]) / 8   for j <= i
// re[n][dd] = r[n][L-1-dd]  (stored that way by gemm outmode 2)
// One block: 16 query rows x full causal key range (tiles of 64).
// LDS budget: 4096+4096+16384+16384+20224+4160 = 65344 B  (< 64 KiB limit!
// previous round was 65792 B -> silent launch failure)
// ---------------------------------------------------------------------------
__device__ __forceinline__ int sw_idx(int row, int d4) {
  return row * 64 + ((d4 ^ (row & 15)) << 2);
}

__global__ __launch_bounds__(256) void attn_kernel(
    const float* __restrict__ q, const float* __restrict__ k, const float* __restrict__ v,
    const float* __restrict__ re, const float* __restrict__ cb, const float* __restrict__ pb,
    float* __restrict__ out)
{
  __shared__ __align__(16) float qc[16 * 64];
  __shared__ __align__(16) float qp[16 * 64];
  __shared__ __align__(16) float kt[64 * 64];
  __shared__ __align__(16) float vt[64 * 64];
  __shared__ __align__(16) float ret[79 * 64];
  __shared__ float pl[16 * 65];

  const int t = threadIdx.x;
  const int i0 = blockIdx.x * 16;
  const int bn = blockIdx.y;           // b*NH + n
  const int b = bn >> 3, n = bn & 7;
  const int ri = t >> 4, l16 = t & 15;

  // load Q tile, build qc/qp (swizzled)
  {
    int row = t >> 4, d4 = t & 15;
    const float* qptr = q + ((size_t)bn * LSEQ + i0 + row) * DH + (d4 << 2);
    float4 qv = *(const float4*)qptr;
    float4 c4 = *(const float4*)(cb + n * DH + (d4 << 2));
    float4 p4 = *(const float4*)(pb + n * DH + (d4 << 2));
    float4 a, bb;
    a.x = qv.x + c4.x; a.y = qv.y + c4.y; a.z = qv.z + c4.z; a.w = qv.w + c4.w;
    bb.x = qv.x + p4.x; bb.y = qv.y + p4.y; bb.z = qv.z + p4.z; bb.w = qv.w + p4.w;
    *(float4*)(qc + sw_idx(row, d4)) = a;
    *(float4*)(qp + sw_idx(row, d4)) = bb;
  }
  __syncthreads();

  float acc0 = 0.0f, acc1 = 0.0f, acc2 = 0.0f, acc3 = 0.0f;
  float m_i = NEGBIG, l_i = 0.0f;   // online-softmax state, uniform per 16-lane group
  const int iabs = i0 + ri;

  for (int j0 = 0; j0 <= i0; j0 += 64) {
    // ---- load K and V tiles (swizzled) ----
    {
      int row = t >> 2, f = (t & 3) << 2;
      const float* kp = k + ((size_t)bn * LSEQ + j0 + row) * DH;
      const float* vp = v + ((size_t)bn * LSEQ + j0 + row) * DH;
      #pragma unroll
      for (int u = 0; u < 4; ++u) {
        int d4 = f + u;
        *(float4*)(kt + sw_idx(row, d4)) = *(const float4*)(kp + (d4 << 2));
        *(float4*)(vt + sw_idx(row, d4)) = *(const float4*)(vp + (d4 << 2));
      }
    }
    // ---- load relative-position band: rows 0..78, drel = i0-j0-63+row ----
    {
      int basei = i0 - j0 - 63;
      #pragma unroll
      for (int it = 0; it < 5; ++it) {
        int e = t + it * 256;
        int row = e >> 4, d4 = e & 15;
        if (row < 79) {
          int drel = basei + row;
          float4 val = {0.f, 0.f, 0.f, 0.f};
          if (drel >= 0 && drel < LSEQ)
            val = *(const float4*)(re + ((size_t)n * LSEQ + drel) * DH + (d4 << 2));
          *(float4*)(ret + sw_idx(row, d4)) = val;
        }
      }
    }
    __syncthreads();

    // ---- scores: each thread does 4 j's (jj = l16 + 16u) ----
    float s0 = 0.f, s1 = 0.f, s2 = 0.f, s3 = 0.f;
    const int rbase = ri + 63;
    for (int d4 = 0; d4 < 16; ++d4) {
      float4 q4 = *(const float4*)(qc + sw_idx(ri, d4));
      float4 p4 = *(const float4*)(qp + sw_idx(ri, d4));
      #pragma unroll
      for (int u = 0; u < 4; ++u) {
        int jj = l16 + (u << 4);
        float4 k4 = *(const float4*)(kt + sw_idx(jj, d4));
        float4 r4 = *(const float4*)(ret + sw_idx(rbase - jj, d4));
        float ds = q4.x * k4.x + q4.y * k4.y + q4.z * k4.z + q4.w * k4.w
                 + p4.x * r4.x + p4.y * r4.y + p4.z * r4.z + p4.w * r4.w;
        if (u == 0) s0 += ds; else if (u == 1) s1 += ds; else if (u == 2) s2 += ds; else s3 += ds;
      }
    }
    float sv[4] = { s0, s1, s2, s3 };
    int valid[4];
    #pragma unroll
    for (int u = 0; u < 4; ++u) {
      int j = j0 + l16 + (u << 4);
      valid[u] = (j <= iabs);
      sv[u] = valid[u] ? sv[u] * 0.125f : NEGBIG;
    }
    float tm = fmaxf(fmaxf(sv[0], sv[1]), fmaxf(sv[2], sv[3]));
    #pragma unroll
    for (int off = 8; off >= 1; off >>= 1) tm = fmaxf(tm, __shfl_xor(tm, off, 64));
    float m_new = fmaxf(m_i, tm);
    float alpha = expf(m_i - m_new);
    float pr[4]; float rs = 0.f;
    #pragma unroll
    for (int u = 0; u < 4; ++u) {
      pr[u] = valid[u] ? expf(sv[u] - m_new) : 0.0f;
      rs += pr[u];
    }
    #pragma unroll
    for (int off = 8; off >= 1; off >>= 1) rs += __shfl_xor(rs, off, 64);
    m_i = m_new;
    l_i = alpha * l_i + rs;
    #pragma unroll
    for (int u = 0; u < 4; ++u) pl[ri * 65 + l16 + (u << 4)] = pr[u];
    // pl produced and consumed within the same wave's 16-lane group (DS ops
    // complete in order within a wave): no barrier needed
    acc0 *= alpha; acc1 *= alpha; acc2 *= alpha; acc3 *= alpha;
    for (int j = 0; j < 64; ++j) {
      float p = pl[ri * 65 + j];
      float4 v4 = *(const float4*)(vt + sw_idx(j, l16));
      acc0 += p * v4.x; acc1 += p * v4.y; acc2 += p * v4.z; acc3 += p * v4.w;
    }
    __syncthreads();   // before next tile overwrites kt/vt/ret
  }

  float linv = 1.0f / l_i;
  float4 o; o.x = acc0 * linv; o.y = acc1 * linv; o.z = acc2 * linv; o.w = acc3 * linv;
  // out layout (B, L, H): fold transpose(0,2,1,3)
  *(float4*)(out + ((size_t)(b * LSEQ + i0 + ri)) * HDIM + n * DH + (l16 << 2)) = o;
}

// ---------------------------------------------------------------------------
// LayerNorm over last dim (512), optional residual add: out = LN(x + res)
// ---------------------------------------------------------------------------
__global__ __launch_bounds__(256) void ln_kernel(
    const float* __restrict__ xin, const float* __restrict__ res,
    const float* __restrict__ w, const float* __restrict__ bb,
    float* __restrict__ out)
{
  __shared__ float red[8];
  const int row = blockIdx.x, t = threadIdx.x;
  const size_t base = (size_t)row * 512;
  float v0 = xin[base + t], v1 = xin[base + t + 256];
  if (res) { v0 += res[base + t]; v1 += res[base + t + 256]; }
  float s = v0 + v1;
  #pragma unroll
  for (int off = 32; off >= 1; off >>= 1) s += __shfl_xor(s, off, 64);
  if ((t & 63) == 0) red[t >> 6] = s;
  __syncthreads();
  float mean = (red[0] + red[1] + red[2] + red[3]) * (1.0f / 512.0f);
  float d0 = v0 - mean, d1 = v1 - mean;
  float s2 = d0 * d0 + d1 * d1;
  #pragma unroll
  for (int off = 32; off >= 1; off >>= 1) s2 += __shfl_xor(s2, off, 64);
  if ((t & 63) == 0) red[4 + (t >> 6)] = s2;
  __syncthreads();
  float var = (red[4] + red[5] + red[6] + red[7]) * (1.0f / 512.0f);
  float inv = 1.0f / sqrtf(var + 1e-12f);
  out[base + t] = w[t] * d0 * inv + bb[t];
  out[base + t + 256] = w[t + 256] * d1 * inv + bb[t + 256];
}

// ---------------------------------------------------------------------------
extern "C" void kernel_launch(void* const* d_in, const int* in_sizes, int n_in,
                              void* d_out, int out_size, void* d_ws, size_t ws_size,
                              hipStream_t stream)
{
  (void)in_sizes; (void)n_in; (void)out_size; (void)ws_size;
  const float* x   = (const float*)d_in[0];
  const float* pos = (const float*)d_in[1];
  const float* Wq  = (const float*)d_in[2];
  const float* bq  = (const float*)d_in[3];
  const float* Wk  = (const float*)d_in[4];
  const float* bk  = (const float*)d_in[5];
  const float* Wv  = (const float*)d_in[6];
  const float* bv  = (const float*)d_in[7];
  const float* Wr  = (const float*)d_in[8];
  const float* br  = (const float*)d_in[9];
  const float* cbv = (const float*)d_in[10];
  const float* pbv = (const float*)d_in[11];
  const float* Wc  = (const float*)d_in[12];
  const float* bc  = (const float*)d_in[13];
  const float* W1  = (const float*)d_in[14];
  const float* b1  = (const float*)d_in[15];
  const float* W2  = (const float*)d_in[16];
  const float* b2  = (const float*)d_in[17];
  const float* lnw = (const float*)d_in[18];
  const float* lnb = (const float*)d_in[19];
  float* ws = (float*)d_ws;
  float* outp = (float*)d_out;

  // ws layout (floats): qb[4M] kb[4M] vb[4M] reb[1M]  => 54.5 MB total
  float* qb   = ws;
  float* kb   = ws + 4194304;
  float* vb   = ws + 8388608;
  float* reb  = ws + 12582912;
  float* attn = outp;               // attention output lives in d_out
  float* cpre = qb;                 // reuse q after attention
  float* ab   = kb;                 // reuse k
  float* h1   = vb;                 // reuse v
  float* h2   = qb;                 // reuse cpre after LN1

  dim3 blk(256);
  dim3 gM(8, 128);   // M=8192
  dim3 gR(8, 32);    // M=2048

  // q, k, v projections (outmode 1: (b,n,l,d) layout)
  gemm_kernel<<<gM, blk, 0, stream>>>(x, Wq, bq, nullptr, qb, 8192, 512, 64, 32768, 1, 1, 0);
  gemm_kernel<<<gM, blk, 0, stream>>>(x, Wk, bk, nullptr, kb, 8192, 512, 64, 32768, 1, 1, 0);
  gemm_kernel<<<gM, blk, 0, stream>>>(x, Wv, bv, nullptr, vb, 8192, 512, 64, 32768, 1, 1, 0);
  // r projection, stored distance-reversed (outmode 2)
  gemm_kernel<<<gR, blk, 0, stream>>>(pos, Wr, br, nullptr, reb, 2048, 512, 64, 32768, 1, 2, 0);
  // attention -> d_out
  attn_kernel<<<dim3(128, 32), blk, 0, stream>>>(qb, kb, vb, reb, cbv, pbv, attn);
  // output projection + bias + residual(x)
  gemm_kernel<<<gM, blk, 0, stream>>>(attn, Wc, bc, x, cpre, 8192, 512, 1, 32768, 512, 0, 0);
  // LN1 -> a
  ln_kernel<<<8192, blk, 0, stream>>>(cpre, nullptr, lnw, lnb, ab);
  // FFN
  gemm_kernel<<<gM, blk, 0, stream>>>(ab, W1, b1, nullptr, h1, 8192, 512, 1, 32768, 512, 0, 1);
  gemm_kernel<<<gM, blk, 0, stream>>>(h1, W2, b2, nullptr, h2, 8192, 512, 1, 32768, 512, 0, 0);
  // LN2(a + h2) -> out
  ln_kernel<<<8192, blk, 0, stream>>>(h2, ab, lnw, lnb, outp);
}

// Round 3
// 775.113 us; speedup vs baseline: 4.6465x; 4.6465x over previous
//
#include <hip/hip_runtime.h>
#include <math.h>

#define HDIM 512
#define LSEQ 2048
#define NH 8
#define DH 64
#define NEGBIG (-3.0e38f)

typedef short bf16x8 __attribute__((ext_vector_type(8)));
typedef float f32x4 __attribute__((ext_vector_type(4)));

__device__ __forceinline__ unsigned short f2b(float f) {
  union { float f; unsigned u; } x; x.f = f;
  unsigned r = x.u + 0x7FFF + ((x.u >> 16) & 1);
  return (unsigned short)(r >> 16);
}
__device__ __forceinline__ float b2f(unsigned short u) {
  union { unsigned u; float f; } x; x.u = ((unsigned)u) << 16;
  return x.f;
}

// ---------------------------------------------------------------------------
// fp32 tiled GEMM (unchanged from R2, correctness-proven)
// ---------------------------------------------------------------------------
__global__ __launch_bounds__(256) void gemm_kernel(
    const float* __restrict__ A, const float* __restrict__ B,
    const float* __restrict__ bias, const float* __restrict__ res,
    float* __restrict__ C, int M, int K,
    int sk, int shi, int slo, int outmode, int dogelu)
{
  __shared__ __align__(16) float As[16 * 68];
  __shared__ __align__(16) float Bs[16 * 68];
  const int t = threadIdx.x;
  const int m0 = blockIdx.y * 64, n0 = blockIdx.x * 64;
  const int tx = t & 15, ty = t >> 4;

  float acc[4][4];
  #pragma unroll
  for (int i = 0; i < 4; ++i)
    #pragma unroll
    for (int j = 0; j < 4; ++j) acc[i][j] = 0.0f;

  for (int k0 = 0; k0 < K; k0 += 16) {
    {
      int mm = t >> 2, kb = (t & 3) << 2;
      float4 a4 = *(const float4*)(A + (size_t)(m0 + mm) * K + k0 + kb);
      As[(kb + 0) * 68 + mm] = a4.x;
      As[(kb + 1) * 68 + mm] = a4.y;
      As[(kb + 2) * 68 + mm] = a4.z;
      As[(kb + 3) * 68 + mm] = a4.w;
    }
    {
      int kk = t >> 4, nb = (t & 15) << 2;
      int krow = (k0 + kk) * sk;
      #pragma unroll
      for (int u = 0; u < 4; ++u) {
        int c = n0 + nb + u;
        Bs[kk * 68 + nb + u] = B[krow + (c >> 6) * shi + (c & 63) * slo];
      }
    }
    __syncthreads();
    #pragma unroll
    for (int kk = 0; kk < 16; ++kk) {
      float4 av = *(const float4*)(As + kk * 68 + (ty << 2));
      float4 bv = *(const float4*)(Bs + kk * 68 + (tx << 2));
      acc[0][0] += av.x * bv.x; acc[0][1] += av.x * bv.y; acc[0][2] += av.x * bv.z; acc[0][3] += av.x * bv.w;
      acc[1][0] += av.y * bv.x; acc[1][1] += av.y * bv.y; acc[1][2] += av.y * bv.z; acc[1][3] += av.y * bv.w;
      acc[2][0] += av.z * bv.x; acc[2][1] += av.z * bv.y; acc[2][2] += av.z * bv.z; acc[2][3] += av.z * bv.w;
      acc[3][0] += av.w * bv.x; acc[3][1] += av.w * bv.y; acc[3][2] += av.w * bv.z; acc[3][3] += av.w * bv.w;
    }
    __syncthreads();
  }

  const int cb_ = n0 + (tx << 2);
  float4 bv = *(const float4*)(bias + cb_);
  #pragma unroll
  for (int i = 0; i < 4; ++i) {
    int m = m0 + (ty << 2) + i;
    float vv[4];
    vv[0] = acc[i][0] + bv.x; vv[1] = acc[i][1] + bv.y;
    vv[2] = acc[i][2] + bv.z; vv[3] = acc[i][3] + bv.w;
    if (res) {
      float4 r4 = *(const float4*)(res + (size_t)m * 512 + cb_);
      vv[0] += r4.x; vv[1] += r4.y; vv[2] += r4.z; vv[3] += r4.w;
    }
    if (dogelu) {
      #pragma unroll
      for (int j = 0; j < 4; ++j)
        vv[j] = 0.5f * vv[j] * (1.0f + erff(vv[j] * 0.70710678118654752f));
    }
    float4 o; o.x = vv[0]; o.y = vv[1]; o.z = vv[2]; o.w = vv[3];
    if (outmode == 0) {
      *(float4*)(C + (size_t)m * 512 + cb_) = o;
    } else if (outmode == 1) {
      int b = m >> 11, l = m & 2047, n = cb_ >> 6, d = cb_ & 63;
      *(float4*)(C + (size_t)((b * NH + n) * LSEQ + l) * DH + d) = o;
    } else {
      int n = cb_ >> 6, d = cb_ & 63;
      *(float4*)(C + (size_t)n * (LSEQ * DH) + (size_t)(LSEQ - 1 - m) * DH + d) = o;
    }
  }
}

// ---------------------------------------------------------------------------
// GEMM with bf16 epilogue.
// mode 0: k-proj   -> C1 bf16 [bn,l,d] = acc+bias
// mode 1: q-proj   -> C1 = acc+bias+cb2 ; C2 = acc+bias+pb2   (both bf16 [bn,l,d])
// mode 2: re-proj  -> C1 bf16 [n, 2047-m, d] = acc+bias
// ---------------------------------------------------------------------------
__global__ __launch_bounds__(256) void gemm_bf16(
    const float* __restrict__ A, const float* __restrict__ B,
    const float* __restrict__ bias, const float* __restrict__ cb2,
    const float* __restrict__ pb2,
    unsigned short* __restrict__ C1, unsigned short* __restrict__ C2,
    int M, int K, int sk, int shi, int slo, int mode)
{
  __shared__ __align__(16) float As[16 * 68];
  __shared__ __align__(16) float Bs[16 * 68];
  const int t = threadIdx.x;
  const int m0 = blockIdx.y * 64, n0 = blockIdx.x * 64;
  const int tx = t & 15, ty = t >> 4;

  float acc[4][4];
  #pragma unroll
  for (int i = 0; i < 4; ++i)
    #pragma unroll
    for (int j = 0; j < 4; ++j) acc[i][j] = 0.0f;

  for (int k0 = 0; k0 < K; k0 += 16) {
    {
      int mm = t >> 2, kb = (t & 3) << 2;
      float4 a4 = *(const float4*)(A + (size_t)(m0 + mm) * K + k0 + kb);
      As[(kb + 0) * 68 + mm] = a4.x;
      As[(kb + 1) * 68 + mm] = a4.y;
      As[(kb + 2) * 68 + mm] = a4.z;
      As[(kb + 3) * 68 + mm] = a4.w;
    }
    {
      int kk = t >> 4, nb = (t & 15) << 2;
      int krow = (k0 + kk) * sk;
      #pragma unroll
      for (int u = 0; u < 4; ++u) {
        int c = n0 + nb + u;
        Bs[kk * 68 + nb + u] = B[krow + (c >> 6) * shi + (c & 63) * slo];
      }
    }
    __syncthreads();
    #pragma unroll
    for (int kk = 0; kk < 16; ++kk) {
      float4 av = *(const float4*)(As + kk * 68 + (ty << 2));
      float4 bv = *(const float4*)(Bs + kk * 68 + (tx << 2));
      acc[0][0] += av.x * bv.x; acc[0][1] += av.x * bv.y; acc[0][2] += av.x * bv.z; acc[0][3] += av.x * bv.w;
      acc[1][0] += av.y * bv.x; acc[1][1] += av.y * bv.y; acc[1][2] += av.y * bv.z; acc[1][3] += av.y * bv.w;
      acc[2][0] += av.z * bv.x; acc[2][1] += av.z * bv.y; acc[2][2] += av.z * bv.z; acc[2][3] += av.z * bv.w;
      acc[3][0] += av.w * bv.x; acc[3][1] += av.w * bv.y; acc[3][2] += av.w * bv.z; acc[3][3] += av.w * bv.w;
    }
    __syncthreads();
  }

  const int cb_ = n0 + (tx << 2);
  float4 bv = *(const float4*)(bias + cb_);
  float4 c4 = {0,0,0,0}, p4 = {0,0,0,0};
  if (mode == 1) {
    c4 = *(const float4*)(cb2 + cb_);
    p4 = *(const float4*)(pb2 + cb_);
  }
  #pragma unroll
  for (int i = 0; i < 4; ++i) {
    int m = m0 + (ty << 2) + i;
    float vv[4];
    vv[0] = acc[i][0] + bv.x; vv[1] = acc[i][1] + bv.y;
    vv[2] = acc[i][2] + bv.z; vv[3] = acc[i][3] + bv.w;
    int n = cb_ >> 6, d = cb_ & 63;
    if (mode == 2) {
      size_t dst = (size_t)n * (LSEQ * DH) + (size_t)(LSEQ - 1 - m) * DH + d;
      ushort4 o;
      o.x = f2b(vv[0]); o.y = f2b(vv[1]); o.z = f2b(vv[2]); o.w = f2b(vv[3]);
      *(ushort4*)(C1 + dst) = o;
    } else {
      int b = m >> 11, l = m & 2047;
      size_t dst = (size_t)((b * NH + n) * LSEQ + l) * DH + d;
      if (mode == 0) {
        ushort4 o;
        o.x = f2b(vv[0]); o.y = f2b(vv[1]); o.z = f2b(vv[2]); o.w = f2b(vv[3]);
        *(ushort4*)(C1 + dst) = o;
      } else {
        ushort4 oc, op;
        oc.x = f2b(vv[0] + c4.x); oc.y = f2b(vv[1] + c4.y);
        oc.z = f2b(vv[2] + c4.z); oc.w = f2b(vv[3] + c4.w);
        op.x = f2b(vv[0] + p4.x); op.y = f2b(vv[1] + p4.y);
        op.z = f2b(vv[2] + p4.z); op.w = f2b(vv[3] + p4.w);
        *(ushort4*)(C1 + dst) = oc;
        *(ushort4*)(C2 + dst) = op;
      }
    }
  }
}

// ---------------------------------------------------------------------------
// Transpose V: vb fp32 [bn, l, d=64] -> vtb bf16 [bn, d, l=2048]
// grid (ltile=32, bn=32), 256 threads, 64x64 tile
// ---------------------------------------------------------------------------
__global__ __launch_bounds__(256) void transpose_v(
    const float* __restrict__ vb, unsigned short* __restrict__ vtb)
{
  __shared__ float tile[64][65];
  const int t = threadIdx.x;
  const int l0 = blockIdx.x * 64;
  const int bn = blockIdx.y;
  #pragma unroll
  for (int it = 0; it < 4; ++it) {
    int row = it * 16 + (t >> 4), col = (t & 15) * 4;
    float4 v4 = *(const float4*)(vb + ((size_t)bn * LSEQ + l0 + row) * DH + col);
    tile[row][col] = v4.x; tile[row][col + 1] = v4.y;
    tile[row][col + 2] = v4.z; tile[row][col + 3] = v4.w;
  }
  __syncthreads();
  #pragma unroll
  for (int it = 0; it < 4; ++it) {
    int d = it * 16 + (t >> 4), lc = (t & 15) * 4;
    ushort4 o;
    o.x = f2b(tile[lc + 0][d]); o.y = f2b(tile[lc + 1][d]);
    o.z = f2b(tile[lc + 2][d]); o.w = f2b(tile[lc + 3][d]);
    *(ushort4*)(vtb + ((size_t)bn * DH + d) * LSEQ + l0 + lc) = o;
  }
}

// ---------------------------------------------------------------------------
// MFMA flash attention with Transformer-XL relative positions.
// Block: 64 q-rows (4 waves x 16), j-tiles of 64 keys.
// score[i,j] = (qc_i.k_j + T[i, i-j]) / 8,  T[i,dd] = qp_i . re[dd]
// Fragment layouts (verified, m89/m91/m120): A/B lane&15 = non-contraction,
// quad*8+j = contraction; C/D col=lane&15, row=quad*4+reg.
// LDS: Ks 9216 + Vts 9216 + Res 18432 + Tb 10752 + Pb 9216 = 56832 B < 64 KiB
// ---------------------------------------------------------------------------
__global__ __launch_bounds__(256, 2) void attn_mfma(
    const unsigned short* __restrict__ qcb, const unsigned short* __restrict__ qpb,
    const unsigned short* __restrict__ kbb, const unsigned short* __restrict__ vtb,
    const unsigned short* __restrict__ rebb, float* __restrict__ out)
{
  __shared__ __align__(16) unsigned short Ks[64 * 72];
  __shared__ __align__(16) unsigned short Vts[64 * 72];
  __shared__ __align__(16) unsigned short Res[128 * 72];
  __shared__ __align__(16) unsigned short Tb[4 * 16 * 84];
  __shared__ __align__(16) unsigned short Pb[4 * 16 * 72];

  const int t = threadIdx.x;
  const int bn = blockIdx.x;
  const int b = bn >> 3, n = bn & 7;
  const int ib = 31 - blockIdx.y;       // heavy blocks dispatched first
  const int i0 = ib * 64;
  const int w = t >> 6;
  const int lane = t & 63;
  const int l15 = lane & 15, quad = lane >> 4;

  // Q fragments (registers, whole kernel): rows I = i0+16w+l15, k = quad*8+32*kk
  bf16x8 qcf[2], qpf[2];
  {
    size_t base = ((size_t)bn * LSEQ + i0 + 16 * w + l15) * DH + quad * 8;
    qcf[0] = *(const bf16x8*)(qcb + base);
    qcf[1] = *(const bf16x8*)(qcb + base + 32);
    qpf[0] = *(const bf16x8*)(qpb + base);
    qpf[1] = *(const bf16x8*)(qpb + base + 32);
  }

  f32x4 Of[4];
  #pragma unroll
  for (int s = 0; s < 4; ++s) Of[s] = (f32x4){0.f, 0.f, 0.f, 0.f};
  float m_r[4] = {NEGBIG, NEGBIG, NEGBIG, NEGBIG};
  float l_r[4] = {0.f, 0.f, 0.f, 0.f};

  unsigned short* Tw = Tb + w * 16 * 84;
  unsigned short* Pw = Pb + w * 16 * 72;
  const int Ibase = i0 + 16 * w;
  const int nt = ib + 1;

  for (int tt = 0; tt < nt; ++tt) {
    const int j0 = tt * 64;
    const int db = i0 - j0;
    __syncthreads();
    // ---- stage K[j][d] and V^T[d][j] (16-elem XOR-swizzled groups) ----
    {
      int r = t >> 2, gl = t & 3;
      int phys = (gl ^ (r & 3)) * 16;
      const int4* sk_ = (const int4*)(kbb + ((size_t)bn * LSEQ + j0 + r) * DH + gl * 16);
      int4 a0 = sk_[0], a1 = sk_[1];
      unsigned short* dk = Ks + r * 72 + phys;
      *(int4*)(dk) = a0; *(int4*)(dk + 8) = a1;
      const int4* sv_ = (const int4*)(vtb + ((size_t)bn * DH + r) * LSEQ + j0 + gl * 16);
      int4 b0 = sv_[0], b1 = sv_[1];
      unsigned short* dv = Vts + r * 72 + phys;
      *(int4*)(dv) = b0; *(int4*)(dv + 8) = b1;
    }
    // ---- stage re distance band: row r <-> dist db-63+r, r=0..127 ----
    {
      int r = t >> 1, h = t & 1;
      int dist = db - 63 + r;
      #pragma unroll
      for (int gi = 0; gi < 2; ++gi) {
        int gl = h * 2 + gi;
        unsigned short* dr = Res + r * 72 + ((gl ^ (r & 3)) * 16);
        if (dist >= 0 && dist < LSEQ) {
          const int4* sr = (const int4*)(rebb + ((size_t)n * LSEQ + dist) * DH + gl * 16);
          *(int4*)(dr) = sr[0]; *(int4*)(dr + 8) = sr[1];
        } else {
          int4 z = {0, 0, 0, 0};
          *(int4*)(dr) = z; *(int4*)(dr + 8) = z;
        }
      }
    }
    __syncthreads();

    // ---- content scores: 4 subtiles ----
    f32x4 Sf[4];
    #pragma unroll
    for (int s = 0; s < 4; ++s) {
      f32x4 acc = {0.f, 0.f, 0.f, 0.f};
      int row = 16 * s + l15;
      #pragma unroll
      for (int kk = 0; kk < 2; ++kk) {
        int g = (quad >> 1) + 2 * kk;
        bf16x8 bfr = *(const bf16x8*)(Ks + row * 72 + ((g ^ (row & 3)) * 16) + (quad & 1) * 8);
        acc = __builtin_amdgcn_mfma_f32_16x16x32_bf16(qcf[kk], bfr, acc, 0, 0, 0);
      }
      Sf[s] = acc;
    }
    // ---- positional T = qp . re_band^T : 5 subtiles -> Tb (bf16) ----
    #pragma unroll
    for (int s = 0; s < 5; ++s) {
      f32x4 acc = {0.f, 0.f, 0.f, 0.f};
      int row = 16 * w + 16 * s + l15;
      #pragma unroll
      for (int kk = 0; kk < 2; ++kk) {
        int g = (quad >> 1) + 2 * kk;
        bf16x8 bfr = *(const bf16x8*)(Res + row * 72 + ((g ^ (row & 3)) * 16) + (quad & 1) * 8);
        acc = __builtin_amdgcn_mfma_f32_16x16x32_bf16(qpf[kk], bfr, acc, 0, 0, 0);
      }
      #pragma unroll
      for (int r = 0; r < 4; ++r) {
        float val = acc[r];
        float other = __shfl_xor(val, 1, 64);
        if ((lane & 1) == 0) {
          int i = quad * 4 + r;
          unsigned pack = (unsigned)f2b(val) | ((unsigned)f2b(other) << 16);
          *(unsigned*)(Tw + i * 84 + 16 * s + l15) = pack;
        }
      }
    }
    asm volatile("s_waitcnt lgkmcnt(0)" ::: "memory");

    // ---- assemble scores, online softmax (C-layout: row=quad*4+r, col=l15) ----
    float p_s[4][4];
    float alpha[4];
    {
      float sc[4][4];
      #pragma unroll
      for (int s = 0; s < 4; ++s)
        #pragma unroll
        for (int r = 0; r < 4; ++r) {
          int i = quad * 4 + r;
          float tval = b2f(Tw[i * 84 + 63 + i - 16 * s - l15]);
          float v = (Sf[s][r] + tval) * 0.125f;
          int j = j0 + 16 * s + l15;
          sc[s][r] = (j <= Ibase + i) ? v : NEGBIG;
        }
      #pragma unroll
      for (int r = 0; r < 4; ++r) {
        float mx = fmaxf(fmaxf(sc[0][r], sc[1][r]), fmaxf(sc[2][r], sc[3][r]));
        #pragma unroll
        for (int off = 8; off >= 1; off >>= 1) mx = fmaxf(mx, __shfl_xor(mx, off, 64));
        float mn = fmaxf(m_r[r], mx);
        alpha[r] = __expf(m_r[r] - mn);
        m_r[r] = mn;
        float rs = 0.f;
        #pragma unroll
        for (int s = 0; s < 4; ++s) {
          float p = __expf(sc[s][r] - mn);
          p_s[s][r] = p; rs += p;
        }
        #pragma unroll
        for (int off = 8; off >= 1; off >>= 1) rs += __shfl_xor(rs, off, 64);
        l_r[r] = l_r[r] * alpha[r] + rs;
      }
      // write P (bf16, pair-packed, group-XOR layout)
      #pragma unroll
      for (int s = 0; s < 4; ++s)
        #pragma unroll
        for (int r = 0; r < 4; ++r) {
          float val = p_s[s][r];
          float other = __shfl_xor(val, 1, 64);
          if ((lane & 1) == 0) {
            int i = quad * 4 + r;
            unsigned pack = (unsigned)f2b(val) | ((unsigned)f2b(other) << 16);
            *(unsigned*)(Pw + i * 72 + ((s ^ (i & 3)) * 16) + l15) = pack;
          }
        }
      #pragma unroll
      for (int s = 0; s < 4; ++s)
        #pragma unroll
        for (int r = 0; r < 4; ++r) Of[s][r] *= alpha[r];
    }
    asm volatile("s_waitcnt lgkmcnt(0)" ::: "memory");

    // ---- PV: O += P . V ----
    #pragma unroll
    for (int kk = 0; kk < 2; ++kk) {
      int g = (quad >> 1) + 2 * kk;
      bf16x8 pa = *(const bf16x8*)(Pw + l15 * 72 + ((g ^ (l15 & 3)) * 16) + (quad & 1) * 8);
      #pragma unroll
      for (int s = 0; s < 4; ++s) {
        int d = 16 * s + l15;
        bf16x8 vb8 = *(const bf16x8*)(Vts + d * 72 + ((g ^ (d & 3)) * 16) + (quad & 1) * 8);
        Of[s] = __builtin_amdgcn_mfma_f32_16x16x32_bf16(pa, vb8, Of[s], 0, 0, 0);
      }
    }
  }

  // ---- epilogue: normalize, write out (B,L,H) with head fold ----
  #pragma unroll
  for (int r = 0; r < 4; ++r) {
    float linv = 1.0f / l_r[r];
    int I = Ibase + quad * 4 + r;
    size_t base = ((size_t)b * LSEQ + I) * HDIM + n * DH;
    #pragma unroll
    for (int s = 0; s < 4; ++s)
      out[base + 16 * s + l15] = Of[s][r] * linv;
  }
}

// ---------------------------------------------------------------------------
// LayerNorm (unchanged)
// ---------------------------------------------------------------------------
__global__ __launch_bounds__(256) void ln_kernel(
    const float* __restrict__ xin, const float* __restrict__ res,
    const float* __restrict__ w, const float* __restrict__ bb,
    float* __restrict__ out)
{
  __shared__ float red[8];
  const int row = blockIdx.x, t = threadIdx.x;
  const size_t base = (size_t)row * 512;
  float v0 = xin[base + t], v1 = xin[base + t + 256];
  if (res) { v0 += res[base + t]; v1 += res[base + t + 256]; }
  float s = v0 + v1;
  #pragma unroll
  for (int off = 32; off >= 1; off >>= 1) s += __shfl_xor(s, off, 64);
  if ((t & 63) == 0) red[t >> 6] = s;
  __syncthreads();
  float mean = (red[0] + red[1] + red[2] + red[3]) * (1.0f / 512.0f);
  float d0 = v0 - mean, d1 = v1 - mean;
  float s2 = d0 * d0 + d1 * d1;
  #pragma unroll
  for (int off = 32; off >= 1; off >>= 1) s2 += __shfl_xor(s2, off, 64);
  if ((t & 63) == 0) red[4 + (t >> 6)] = s2;
  __syncthreads();
  float var = (red[4] + red[5] + red[6] + red[7]) * (1.0f / 512.0f);
  float inv = 1.0f / sqrtf(var + 1e-12f);
  out[base + t] = w[t] * d0 * inv + bb[t];
  out[base + t + 256] = w[t + 256] * d1 * inv + bb[t + 256];
}

// ---------------------------------------------------------------------------
extern "C" void kernel_launch(void* const* d_in, const int* in_sizes, int n_in,
                              void* d_out, int out_size, void* d_ws, size_t ws_size,
                              hipStream_t stream)
{
  (void)in_sizes; (void)n_in; (void)out_size; (void)ws_size;
  const float* x   = (const float*)d_in[0];
  const float* pos = (const float*)d_in[1];
  const float* Wq  = (const float*)d_in[2];
  const float* bq  = (const float*)d_in[3];
  const float* Wk  = (const float*)d_in[4];
  const float* bk  = (const float*)d_in[5];
  const float* Wv  = (const float*)d_in[6];
  const float* bv  = (const float*)d_in[7];
  const float* Wr  = (const float*)d_in[8];
  const float* br  = (const float*)d_in[9];
  const float* cbv = (const float*)d_in[10];
  const float* pbv = (const float*)d_in[11];
  const float* Wc  = (const float*)d_in[12];
  const float* bc  = (const float*)d_in[13];
  const float* W1  = (const float*)d_in[14];
  const float* b1  = (const float*)d_in[15];
  const float* W2  = (const float*)d_in[16];
  const float* b2  = (const float*)d_in[17];
  const float* lnw = (const float*)d_in[18];
  const float* lnb = (const float*)d_in[19];
  char* ws = (char*)d_ws;
  float* outp = (float*)d_out;

  // byte offsets in ws (peak 52.4 MB; R2 used 54.5 MB successfully)
  unsigned short* qcb  = (unsigned short*)(ws);                    //  8.39 MB
  unsigned short* qpb  = (unsigned short*)(ws + 8388608);          //  8.39 MB
  unsigned short* kbb  = (unsigned short*)(ws + 16777216);         //  8.39 MB
  unsigned short* rebb = (unsigned short*)(ws + 25165824);         //  2.10 MB
  unsigned short* vtb  = (unsigned short*)(ws + 27262976);         //  8.39 MB
  float*          vb   = (float*)(ws + 35651584);                  // 16.78 MB
  // post-attention fp32 overlays (all bf16 buffers dead by then)
  float* cpre = (float*)(ws);                                      // 16.78 MB
  float* ab   = (float*)(ws + 16777216);                           // 16.78 MB
  float* h1   = (float*)(ws + 33554432);                           // 16.78 MB
  float* h2   = (float*)(ws);                                      // reuse cpre

  dim3 blk(256);
  dim3 gM(8, 128);   // M=8192
  dim3 gR(8, 32);    // M=2048

  // projections
  gemm_bf16<<<gM, blk, 0, stream>>>(x, Wq, bq, cbv, pbv, qcb, qpb, 8192, 512, 64, 32768, 1, 1);
  gemm_bf16<<<gM, blk, 0, stream>>>(x, Wk, bk, nullptr, nullptr, kbb, nullptr, 8192, 512, 64, 32768, 1, 0);
  gemm_kernel<<<gM, blk, 0, stream>>>(x, Wv, bv, nullptr, vb, 8192, 512, 64, 32768, 1, 1, 0);
  gemm_bf16<<<gR, blk, 0, stream>>>(pos, Wr, br, nullptr, nullptr, rebb, nullptr, 2048, 512, 64, 32768, 1, 2);
  transpose_v<<<dim3(32, 32), blk, 0, stream>>>(vb, vtb);
  // attention -> d_out
  attn_mfma<<<dim3(32, 32), blk, 0, stream>>>(qcb, qpb, kbb, vtb, rebb, outp);
  // output projection + residual(x)
  gemm_kernel<<<gM, blk, 0, stream>>>(outp, Wc, bc, x, cpre, 8192, 512, 1, 32768, 512, 0, 0);
  ln_kernel<<<8192, blk, 0, stream>>>(cpre, nullptr, lnw, lnb, ab);
  // FFN
  gemm_kernel<<<gM, blk, 0, stream>>>(ab, W1, b1, nullptr, h1, 8192, 512, 1, 32768, 512, 0, 1);
  gemm_kernel<<<gM, blk, 0, stream>>>(h1, W2, b2, nullptr, h2, 8192, 512, 1, 32768, 512, 0, 0);
  ln_kernel<<<8192, blk, 0, stream>>>(h2, ab, lnw, lnb, outp);
}

// Round 4
// 555.966 us; speedup vs baseline: 6.4780x; 1.3942x over previous
//
#include <hip/hip_runtime.h>
#include <math.h>

#define HDIM 512
#define LSEQ 2048
#define NH 8
#define DH 64
#define NEGBIG (-3.0e38f)

#define MODE_QDUAL  0
#define MODE_KV     1
#define MODE_VT     2
#define MODE_RE     3
#define MODE_F32RES 4
#define MODE_GELU   5

typedef short bf16x8 __attribute__((ext_vector_type(8)));
typedef float f32x4 __attribute__((ext_vector_type(4)));

__device__ __forceinline__ unsigned short f2b(float f) {
  union { float f; unsigned u; } x; x.f = f;
  unsigned r = x.u + 0x7FFF + ((x.u >> 16) & 1);
  return (unsigned short)(r >> 16);
}
__device__ __forceinline__ float b2f(unsigned short u) {
  union { unsigned u; float f; } x; x.u = ((unsigned)u) << 16;
  return x.f;
}

// ---------------------------------------------------------------------------
// fp32 -> bf16 vector convert (x, pos_enc)
// ---------------------------------------------------------------------------
__global__ __launch_bounds__(256) void conv_f32_bf16(
    const float* __restrict__ in, unsigned short* __restrict__ out, int n4)
{
  int idx = blockIdx.x * 256 + threadIdx.x;
  if (idx < n4) {
    float4 v = ((const float4*)in)[idx];
    ushort4 o; o.x = f2b(v.x); o.y = f2b(v.y); o.z = f2b(v.z); o.w = f2b(v.w);
    ((ushort4*)out)[idx] = o;
  }
}

// ---------------------------------------------------------------------------
// Weight prep: widx 0..3 (Wq,Wk,Wv,Wr [n,h,d] -> bf16 [n*64+d][h] B^T form),
//              widx 4..6 (Wc,W1,W2 [c,k] row-major -> bf16 straight convert)
// grid (64, 7)
// ---------------------------------------------------------------------------
__global__ __launch_bounds__(256) void conv_weights(
    const float* __restrict__ Wq, const float* __restrict__ Wk,
    const float* __restrict__ Wv, const float* __restrict__ Wr,
    const float* __restrict__ Wc, const float* __restrict__ W1,
    const float* __restrict__ W2, unsigned short* __restrict__ wT)
{
  const int widx = blockIdx.y;
  const float* src = (widx == 0) ? Wq : (widx == 1) ? Wk : (widx == 2) ? Wv :
                     (widx == 3) ? Wr : (widx == 4) ? Wc : (widx == 5) ? W1 : W2;
  unsigned short* dst = wT + (size_t)widx * 262144;
  const int t = threadIdx.x;
  const int tile = blockIdx.x;

  if (widx < 4) {
    // transpose [n, h, d] -> [(n*64+d), h]
    __shared__ float td[64][65];
    const int h0 = (tile >> 3) * 64;
    const int n  = tile & 7;
    #pragma unroll
    for (int it = 0; it < 4; ++it) {
      int row = it * 16 + (t >> 4), dc = (t & 15) * 4;
      float4 v = *(const float4*)(src + (size_t)n * 32768 + (size_t)(h0 + row) * 64 + dc);
      td[row][dc] = v.x; td[row][dc + 1] = v.y; td[row][dc + 2] = v.z; td[row][dc + 3] = v.w;
    }
    __syncthreads();
    #pragma unroll
    for (int it = 0; it < 4; ++it) {
      int d = it * 16 + (t >> 4), h4 = (t & 15) * 4;
      ushort4 o;
      o.x = f2b(td[h4 + 0][d]); o.y = f2b(td[h4 + 1][d]);
      o.z = f2b(td[h4 + 2][d]); o.w = f2b(td[h4 + 3][d]);
      *(ushort4*)(dst + (size_t)(n * 64 + d) * 512 + h0 + h4) = o;
    }
  } else {
    // straight convert, 1024 float4 per block
    #pragma unroll
    for (int i = 0; i < 4; ++i) {
      int f4 = tile * 1024 + i * 256 + t;
      float4 v = ((const float4*)src)[f4];
      ushort4 o; o.x = f2b(v.x); o.y = f2b(v.y); o.z = f2b(v.z); o.w = f2b(v.w);
      ((ushort4*)dst)[f4] = o;
    }
  }
}

// ---------------------------------------------------------------------------
// LDS-free MFMA GEMM:  C[m,c] = epi( sum_k A[m,k]*BT[c,k] + bias[c] ... )
// A bf16 [M x 512] row-major, BT bf16 [512 x 512] row-major (= W[c,k]).
// Block = 4 waves, each wave one 64x64 tile via direct b128 global loads
// (A/B fragment layouts are contiguous 16B in this storage). K-loop
// software-pipelined lookahead-2. No LDS, no barriers.
// ---------------------------------------------------------------------------
__global__ __launch_bounds__(256) void gemm_mfma(
    const unsigned short* __restrict__ A, const unsigned short* __restrict__ BT,
    const float* __restrict__ bias, const float* __restrict__ cb2,
    const float* __restrict__ pb2, const float* __restrict__ resf,
    const unsigned short* __restrict__ res16,
    void* __restrict__ C1v, unsigned short* __restrict__ C2,
    int M, int mode)
{
  const int t = threadIdx.x;
  const int w = t >> 6, lane = t & 63;
  const int l15 = lane & 15, quad = lane >> 4;
  const int r0 = blockIdx.y * 128 + (w >> 1) * 64;
  const int c0 = blockIdx.x * 128 + (w & 1) * 64;

  const unsigned short* Ab = A + (size_t)(r0 + l15) * 512 + quad * 8;
  const unsigned short* Bb = BT + (size_t)(c0 + l15) * 512 + quad * 8;

  f32x4 acc[4][4];
  #pragma unroll
  for (int sr = 0; sr < 4; ++sr)
    #pragma unroll
    for (int sc = 0; sc < 4; ++sc) acc[sr][sc] = (f32x4){0.f, 0.f, 0.f, 0.f};

  bf16x8 af[3][4], bf[3][4];
  #pragma unroll
  for (int sl = 0; sl < 2; ++sl) {
    #pragma unroll
    for (int s = 0; s < 4; ++s) {
      af[sl][s] = *(const bf16x8*)(Ab + (size_t)s * 16 * 512 + sl * 32);
      bf[sl][s] = *(const bf16x8*)(Bb + (size_t)s * 16 * 512 + sl * 32);
    }
  }

  #pragma unroll
  for (int kk = 0; kk < 16; ++kk) {
    const int cur = kk % 3, nxt = (kk + 2) % 3;
    if (kk + 2 < 16) {
      #pragma unroll
      for (int s = 0; s < 4; ++s) {
        af[nxt][s] = *(const bf16x8*)(Ab + (size_t)s * 16 * 512 + (kk + 2) * 32);
        bf[nxt][s] = *(const bf16x8*)(Bb + (size_t)s * 16 * 512 + (kk + 2) * 32);
      }
    }
    #pragma unroll
    for (int sr = 0; sr < 4; ++sr)
      #pragma unroll
      for (int sc = 0; sc < 4; ++sc)
        acc[sr][sc] = __builtin_amdgcn_mfma_f32_16x16x32_bf16(
            af[cur][sr], bf[cur][sc], acc[sr][sc], 0, 0, 0);
  }

  // ---- epilogue ----
  float* C1f = (float*)C1v;
  unsigned short* C1u = (unsigned short*)C1v;

  #pragma unroll
  for (int sc = 0; sc < 4; ++sc) {
    const int c = c0 + sc * 16 + l15;
    const float bia = bias[c];
    const float cb = (mode == MODE_QDUAL) ? cb2[c] : 0.f;
    const float pb = (mode == MODE_QDUAL) ? pb2[c] : 0.f;
    const int n = c >> 6, d = c & 63;
    #pragma unroll
    for (int sr = 0; sr < 4; ++sr) {
      #pragma unroll
      for (int r = 0; r < 4; ++r) {
        const int m = r0 + sr * 16 + quad * 4 + r;
        float v = acc[sr][sc][r] + bia;
        if (mode == MODE_QDUAL) {
          const int bb = m >> 11, l = m & 2047;
          size_t dstp = ((size_t)(bb * NH + n) * LSEQ + l) * DH + d;
          C1u[dstp] = f2b(v + cb);
          C2[dstp]  = f2b(v + pb);
        } else if (mode == MODE_KV) {
          const int bb = m >> 11, l = m & 2047;
          C1u[((size_t)(bb * NH + n) * LSEQ + l) * DH + d] = f2b(v);
        } else if (mode == MODE_VT) {
          const int bb = m >> 11, l = m & 2047;
          C1u[((size_t)(bb * NH + n) * DH + d) * LSEQ + l] = f2b(v);
        } else if (mode == MODE_RE) {
          C1u[((size_t)n * LSEQ + (LSEQ - 1 - m)) * DH + d] = f2b(v);
        } else if (mode == MODE_F32RES) {
          if (resf)  v += resf[(size_t)m * 512 + c];
          if (res16) v += b2f(res16[(size_t)m * 512 + c]);
          C1f[(size_t)m * 512 + c] = v;
        } else { // MODE_GELU
          v = 0.5f * v * (1.0f + erff(v * 0.70710678118654752f));
          C1u[(size_t)m * 512 + c] = f2b(v);
        }
      }
    }
  }
}

// ---------------------------------------------------------------------------
// MFMA flash attention with Transformer-XL relative positions (R3-proven,
// epilogue now writes bf16 to feed the c-projection GEMM).
// LDS: Ks 9216 + Vts 9216 + Res 18432 + Tb 10752 + Pb 9216 = 56832 B < 64 KiB
// ---------------------------------------------------------------------------
__global__ __launch_bounds__(256, 2) void attn_mfma(
    const unsigned short* __restrict__ qcb, const unsigned short* __restrict__ qpb,
    const unsigned short* __restrict__ kbb, const unsigned short* __restrict__ vtb,
    const unsigned short* __restrict__ rebb, unsigned short* __restrict__ outb)
{
  __shared__ __align__(16) unsigned short Ks[64 * 72];
  __shared__ __align__(16) unsigned short Vts[64 * 72];
  __shared__ __align__(16) unsigned short Res[128 * 72];
  __shared__ __align__(16) unsigned short Tb[4 * 16 * 84];
  __shared__ __align__(16) unsigned short Pb[4 * 16 * 72];

  const int t = threadIdx.x;
  const int bn = blockIdx.x;
  const int b = bn >> 3, n = bn & 7;
  const int ib = 31 - blockIdx.y;       // heavy blocks dispatched first
  const int i0 = ib * 64;
  const int w = t >> 6;
  const int lane = t & 63;
  const int l15 = lane & 15, quad = lane >> 4;

  bf16x8 qcf[2], qpf[2];
  {
    size_t base = ((size_t)bn * LSEQ + i0 + 16 * w + l15) * DH + quad * 8;
    qcf[0] = *(const bf16x8*)(qcb + base);
    qcf[1] = *(const bf16x8*)(qcb + base + 32);
    qpf[0] = *(const bf16x8*)(qpb + base);
    qpf[1] = *(const bf16x8*)(qpb + base + 32);
  }

  f32x4 Of[4];
  #pragma unroll
  for (int s = 0; s < 4; ++s) Of[s] = (f32x4){0.f, 0.f, 0.f, 0.f};
  float m_r[4] = {NEGBIG, NEGBIG, NEGBIG, NEGBIG};
  float l_r[4] = {0.f, 0.f, 0.f, 0.f};

  unsigned short* Tw = Tb + w * 16 * 84;
  unsigned short* Pw = Pb + w * 16 * 72;
  const int Ibase = i0 + 16 * w;
  const int nt = ib + 1;

  for (int tt = 0; tt < nt; ++tt) {
    const int j0 = tt * 64;
    const int db = i0 - j0;
    __syncthreads();
    {
      int r = t >> 2, gl = t & 3;
      int phys = (gl ^ (r & 3)) * 16;
      const int4* sk_ = (const int4*)(kbb + ((size_t)bn * LSEQ + j0 + r) * DH + gl * 16);
      int4 a0 = sk_[0], a1 = sk_[1];
      unsigned short* dk = Ks + r * 72 + phys;
      *(int4*)(dk) = a0; *(int4*)(dk + 8) = a1;
      const int4* sv_ = (const int4*)(vtb + ((size_t)bn * DH + r) * LSEQ + j0 + gl * 16);
      int4 b0 = sv_[0], b1 = sv_[1];
      unsigned short* dv = Vts + r * 72 + phys;
      *(int4*)(dv) = b0; *(int4*)(dv + 8) = b1;
    }
    {
      int r = t >> 1, h = t & 1;
      int dist = db - 63 + r;
      #pragma unroll
      for (int gi = 0; gi < 2; ++gi) {
        int gl = h * 2 + gi;
        unsigned short* dr = Res + r * 72 + ((gl ^ (r & 3)) * 16);
        if (dist >= 0 && dist < LSEQ) {
          const int4* sr = (const int4*)(rebb + ((size_t)n * LSEQ + dist) * DH + gl * 16);
          *(int4*)(dr) = sr[0]; *(int4*)(dr + 8) = sr[1];
        } else {
          int4 z = {0, 0, 0, 0};
          *(int4*)(dr) = z; *(int4*)(dr + 8) = z;
        }
      }
    }
    __syncthreads();

    f32x4 Sf[4];
    #pragma unroll
    for (int s = 0; s < 4; ++s) {
      f32x4 acc = {0.f, 0.f, 0.f, 0.f};
      int row = 16 * s + l15;
      #pragma unroll
      for (int kk = 0; kk < 2; ++kk) {
        int g = (quad >> 1) + 2 * kk;
        bf16x8 bfr = *(const bf16x8*)(Ks + row * 72 + ((g ^ (row & 3)) * 16) + (quad & 1) * 8);
        acc = __builtin_amdgcn_mfma_f32_16x16x32_bf16(qcf[kk], bfr, acc, 0, 0, 0);
      }
      Sf[s] = acc;
    }
    #pragma unroll
    for (int s = 0; s < 5; ++s) {
      f32x4 acc = {0.f, 0.f, 0.f, 0.f};
      int row = 16 * w + 16 * s + l15;
      #pragma unroll
      for (int kk = 0; kk < 2; ++kk) {
        int g = (quad >> 1) + 2 * kk;
        bf16x8 bfr = *(const bf16x8*)(Res + row * 72 + ((g ^ (row & 3)) * 16) + (quad & 1) * 8);
        acc = __builtin_amdgcn_mfma_f32_16x16x32_bf16(qpf[kk], bfr, acc, 0, 0, 0);
      }
      #pragma unroll
      for (int r = 0; r < 4; ++r) {
        float val = acc[r];
        float other = __shfl_xor(val, 1, 64);
        if ((lane & 1) == 0) {
          int i = quad * 4 + r;
          unsigned pack = (unsigned)f2b(val) | ((unsigned)f2b(other) << 16);
          *(unsigned*)(Tw + i * 84 + 16 * s + l15) = pack;
        }
      }
    }
    asm volatile("s_waitcnt lgkmcnt(0)" ::: "memory");

    float p_s[4][4];
    float alpha[4];
    {
      float sc[4][4];
      #pragma unroll
      for (int s = 0; s < 4; ++s)
        #pragma unroll
        for (int r = 0; r < 4; ++r) {
          int i = quad * 4 + r;
          float tval = b2f(Tw[i * 84 + 63 + i - 16 * s - l15]);
          float v = (Sf[s][r] + tval) * 0.125f;
          int j = j0 + 16 * s + l15;
          sc[s][r] = (j <= Ibase + i) ? v : NEGBIG;
        }
      #pragma unroll
      for (int r = 0; r < 4; ++r) {
        float mx = fmaxf(fmaxf(sc[0][r], sc[1][r]), fmaxf(sc[2][r], sc[3][r]));
        #pragma unroll
        for (int off = 8; off >= 1; off >>= 1) mx = fmaxf(mx, __shfl_xor(mx, off, 64));
        float mn = fmaxf(m_r[r], mx);
        alpha[r] = __expf(m_r[r] - mn);
        m_r[r] = mn;
        float rs = 0.f;
        #pragma unroll
        for (int s = 0; s < 4; ++s) {
          float p = __expf(sc[s][r] - mn);
          p_s[s][r] = p; rs += p;
        }
        #pragma unroll
        for (int off = 8; off >= 1; off >>= 1) rs += __shfl_xor(rs, off, 64);
        l_r[r] = l_r[r] * alpha[r] + rs;
      }
      #pragma unroll
      for (int s = 0; s < 4; ++s)
        #pragma unroll
        for (int r = 0; r < 4; ++r) {
          float val = p_s[s][r];
          float other = __shfl_xor(val, 1, 64);
          if ((lane & 1) == 0) {
            int i = quad * 4 + r;
            unsigned pack = (unsigned)f2b(val) | ((unsigned)f2b(other) << 16);
            *(unsigned*)(Pw + i * 72 + ((s ^ (i & 3)) * 16) + l15) = pack;
          }
        }
      #pragma unroll
      for (int s = 0; s < 4; ++s)
        #pragma unroll
        for (int r = 0; r < 4; ++r) Of[s][r] *= alpha[r];
    }
    asm volatile("s_waitcnt lgkmcnt(0)" ::: "memory");

    #pragma unroll
    for (int kk = 0; kk < 2; ++kk) {
      int g = (quad >> 1) + 2 * kk;
      bf16x8 pa = *(const bf16x8*)(Pw + l15 * 72 + ((g ^ (l15 & 3)) * 16) + (quad & 1) * 8);
      #pragma unroll
      for (int s = 0; s < 4; ++s) {
        int d = 16 * s + l15;
        bf16x8 vb8 = *(const bf16x8*)(Vts + d * 72 + ((g ^ (d & 3)) * 16) + (quad & 1) * 8);
        Of[s] = __builtin_amdgcn_mfma_f32_16x16x32_bf16(pa, vb8, Of[s], 0, 0, 0);
      }
    }
  }

  // epilogue: normalize, write bf16 out (B,L,H)
  #pragma unroll
  for (int r = 0; r < 4; ++r) {
    float linv = 1.0f / l_r[r];
    int I = Ibase + quad * 4 + r;
    size_t base = ((size_t)b * LSEQ + I) * HDIM + n * DH;
    #pragma unroll
    for (int s = 0; s < 4; ++s)
      outb[base + 16 * s + l15] = f2b(Of[s][r] * linv);
  }
}

// ---------------------------------------------------------------------------
// LayerNorm over last dim (512): outf (fp32) and/or out16 (bf16), nullable
// ---------------------------------------------------------------------------
__global__ __launch_bounds__(256) void ln_kernel(
    const float* __restrict__ xin, const float* __restrict__ w,
    const float* __restrict__ bb, float* __restrict__ outf,
    unsigned short* __restrict__ out16)
{
  __shared__ float red[8];
  const int row = blockIdx.x, t = threadIdx.x;
  const size_t base = (size_t)row * 512;
  float v0 = xin[base + t], v1 = xin[base + t + 256];
  float s = v0 + v1;
  #pragma unroll
  for (int off = 32; off >= 1; off >>= 1) s += __shfl_xor(s, off, 64);
  if ((t & 63) == 0) red[t >> 6] = s;
  __syncthreads();
  float mean = (red[0] + red[1] + red[2] + red[3]) * (1.0f / 512.0f);
  float d0 = v0 - mean, d1 = v1 - mean;
  float s2 = d0 * d0 + d1 * d1;
  #pragma unroll
  for (int off = 32; off >= 1; off >>= 1) s2 += __shfl_xor(s2, off, 64);
  if ((t & 63) == 0) red[4 + (t >> 6)] = s2;
  __syncthreads();
  float var = (red[4] + red[5] + red[6] + red[7]) * (1.0f / 512.0f);
  float inv = 1.0f / sqrtf(var + 1e-12f);
  float o0 = w[t] * d0 * inv + bb[t];
  float o1 = w[t + 256] * d1 * inv + bb[t + 256];
  if (outf)  { outf[base + t] = o0; outf[base + t + 256] = o1; }
  if (out16) { out16[base + t] = f2b(o0); out16[base + t + 256] = f2b(o1); }
}

// ---------------------------------------------------------------------------
extern "C" void kernel_launch(void* const* d_in, const int* in_sizes, int n_in,
                              void* d_out, int out_size, void* d_ws, size_t ws_size,
                              hipStream_t stream)
{
  (void)in_sizes; (void)n_in; (void)out_size; (void)ws_size;
  const float* x   = (const float*)d_in[0];
  const float* pos = (const float*)d_in[1];
  const float* Wq  = (const float*)d_in[2];
  const float* bq  = (const float*)d_in[3];
  const float* Wk  = (const float*)d_in[4];
  const float* bk  = (const float*)d_in[5];
  const float* Wv  = (const float*)d_in[6];
  const float* bv  = (const float*)d_in[7];
  const float* Wr  = (const float*)d_in[8];
  const float* br  = (const float*)d_in[9];
  const float* cbv = (const float*)d_in[10];
  const float* pbv = (const float*)d_in[11];
  const float* Wc  = (const float*)d_in[12];
  const float* bc  = (const float*)d_in[13];
  const float* W1  = (const float*)d_in[14];
  const float* b1  = (const float*)d_in[15];
  const float* W2  = (const float*)d_in[16];
  const float* b2  = (const float*)d_in[17];
  const float* lnw = (const float*)d_in[18];
  const float* lnb = (const float*)d_in[19];
  char* ws = (char*)d_ws;
  float* outp = (float*)d_out;

  // ws layout (bytes), peak 49.9 MB:
  // 0:        xb  8.39M      (-> ab16 after LN1)
  // 8.39M:    posb 2.10M
  // 10.49M:   wT  7x0.524M = 3.67M   [WqT WkT WvT WrT WcT W1T W2T]
  // 14.16M:   qcb 8.39M     (-> cpre 16.78M spanning qcb+qpb -> h2pre)
  // 22.54M:   qpb 8.39M
  // 30.93M:   kbb 8.39M     (-> h1b after FFN1)
  // 39.32M:   vtb 8.39M
  // 47.71M:   rebb 2.10M
  unsigned short* xb   = (unsigned short*)(ws);
  unsigned short* posb = (unsigned short*)(ws + 8388608);
  unsigned short* wT   = (unsigned short*)(ws + 10485760);
  unsigned short* qcb  = (unsigned short*)(ws + 14155776);
  unsigned short* qpb  = (unsigned short*)(ws + 22544384);
  unsigned short* kbb  = (unsigned short*)(ws + 30932992);
  unsigned short* vtb  = (unsigned short*)(ws + 39321600);
  unsigned short* rebb = (unsigned short*)(ws + 47710208);
  unsigned short* WqT = wT;
  unsigned short* WkT = wT + 262144;
  unsigned short* WvT = wT + 2 * 262144;
  unsigned short* WrT = wT + 3 * 262144;
  unsigned short* WcT = wT + 4 * 262144;
  unsigned short* W1T = wT + 5 * 262144;
  unsigned short* W2T = wT + 6 * 262144;
  // overlays (post-attention)
  unsigned short* attnb = (unsigned short*)d_out;       // bf16 in d_out
  float*          cpre  = (float*)(ws + 14155776);      // over qcb+qpb
  unsigned short* ab16  = (unsigned short*)(ws);        // over xb
  unsigned short* h1b   = (unsigned short*)(ws + 30932992); // over kbb
  float*          h2pre = (float*)(ws + 14155776);      // over cpre

  dim3 blk(256);
  dim3 g8(4, 64);    // M=8192, N=512, 128x128 tiles
  dim3 g2(4, 16);    // M=2048

  conv_f32_bf16<<<4096, blk, 0, stream>>>(x, xb, 1048576);
  conv_f32_bf16<<<1024, blk, 0, stream>>>(pos, posb, 262144);
  conv_weights<<<dim3(64, 7), blk, 0, stream>>>(Wq, Wk, Wv, Wr, Wc, W1, W2, wT);

  gemm_mfma<<<g8, blk, 0, stream>>>(xb, WqT, bq, cbv, pbv, nullptr, nullptr,
                                    qcb, qpb, 8192, MODE_QDUAL);
  gemm_mfma<<<g8, blk, 0, stream>>>(xb, WkT, bk, nullptr, nullptr, nullptr, nullptr,
                                    kbb, nullptr, 8192, MODE_KV);
  gemm_mfma<<<g8, blk, 0, stream>>>(xb, WvT, bv, nullptr, nullptr, nullptr, nullptr,
                                    vtb, nullptr, 8192, MODE_VT);
  gemm_mfma<<<g2, blk, 0, stream>>>(posb, WrT, br, nullptr, nullptr, nullptr, nullptr,
                                    rebb, nullptr, 2048, MODE_RE);

  attn_mfma<<<dim3(32, 32), blk, 0, stream>>>(qcb, qpb, kbb, vtb, rebb, attnb);

  gemm_mfma<<<g8, blk, 0, stream>>>(attnb, WcT, bc, nullptr, nullptr, x, nullptr,
                                    cpre, nullptr, 8192, MODE_F32RES);
  ln_kernel<<<8192, blk, 0, stream>>>(cpre, lnw, lnb, nullptr, ab16);
  gemm_mfma<<<g8, blk, 0, stream>>>(ab16, W1T, b1, nullptr, nullptr, nullptr, nullptr,
                                    h1b, nullptr, 8192, MODE_GELU);
  gemm_mfma<<<g8, blk, 0, stream>>>(h1b, W2T, b2, nullptr, nullptr, nullptr, ab16,
                                    h2pre, nullptr, 8192, MODE_F32RES);
  ln_kernel<<<8192, blk, 0, stream>>>(h2pre, lnw, lnb, outp, nullptr);
}

// Round 5
// 435.869 us; speedup vs baseline: 8.2629x; 1.2755x over previous
//
#include <hip/hip_runtime.h>
#include <math.h>

#define HDIM 512
#define LSEQ 2048
#define NH 8
#define DH 64
#define NEGBIG (-3.0e38f)

#define MODE_QDUAL  0
#define MODE_KV     1
#define MODE_VT     2
#define MODE_RE     3
#define MODE_F32RES 4
#define MODE_GELU   5

typedef short bf16x8 __attribute__((ext_vector_type(8)));
typedef float f32x4 __attribute__((ext_vector_type(4)));

__device__ __forceinline__ unsigned short f2b(float f) {
  union { float f; unsigned u; } x; x.f = f;
  unsigned r = x.u + 0x7FFF + ((x.u >> 16) & 1);
  return (unsigned short)(r >> 16);
}
__device__ __forceinline__ float b2f(unsigned short u) {
  union { unsigned u; float f; } x; x.u = ((unsigned)u) << 16;
  return x.f;
}

// async global->LDS, 16B per lane; LDS dest = wave-uniform base + lane*16
__device__ __forceinline__ void gl_lds16(const void* g, void* l) {
  __builtin_amdgcn_global_load_lds(
      (const __attribute__((address_space(1))) void*)g,
      (__attribute__((address_space(3))) void*)l, 16, 0, 0);
}

// ---------------------------------------------------------------------------
// fp32 -> bf16 vector convert (x, pos_enc)
// ---------------------------------------------------------------------------
__global__ __launch_bounds__(256) void conv_f32_bf16(
    const float* __restrict__ in, unsigned short* __restrict__ out, int n4)
{
  int idx = blockIdx.x * 256 + threadIdx.x;
  if (idx < n4) {
    float4 v = ((const float4*)in)[idx];
    ushort4 o; o.x = f2b(v.x); o.y = f2b(v.y); o.z = f2b(v.z); o.w = f2b(v.w);
    ((ushort4*)out)[idx] = o;
  }
}

// ---------------------------------------------------------------------------
// Weight prep: widx 0..3 (Wq,Wk,Wv,Wr [n,h,d] -> bf16 [n*64+d][h] B^T form),
//              widx 4..6 (Wc,W1,W2 [c,k] row-major -> bf16 straight convert)
// ---------------------------------------------------------------------------
__global__ __launch_bounds__(256) void conv_weights(
    const float* __restrict__ Wq, const float* __restrict__ Wk,
    const float* __restrict__ Wv, const float* __restrict__ Wr,
    const float* __restrict__ Wc, const float* __restrict__ W1,
    const float* __restrict__ W2, unsigned short* __restrict__ wT)
{
  const int widx = blockIdx.y;
  const float* src = (widx == 0) ? Wq : (widx == 1) ? Wk : (widx == 2) ? Wv :
                     (widx == 3) ? Wr : (widx == 4) ? Wc : (widx == 5) ? W1 : W2;
  unsigned short* dst = wT + (size_t)widx * 262144;
  const int t = threadIdx.x;
  const int tile = blockIdx.x;

  if (widx < 4) {
    __shared__ float td[64][65];
    const int h0 = (tile >> 3) * 64;
    const int n  = tile & 7;
    #pragma unroll
    for (int it = 0; it < 4; ++it) {
      int row = it * 16 + (t >> 4), dc = (t & 15) * 4;
      float4 v = *(const float4*)(src + (size_t)n * 32768 + (size_t)(h0 + row) * 64 + dc);
      td[row][dc] = v.x; td[row][dc + 1] = v.y; td[row][dc + 2] = v.z; td[row][dc + 3] = v.w;
    }
    __syncthreads();
    #pragma unroll
    for (int it = 0; it < 4; ++it) {
      int d = it * 16 + (t >> 4), h4 = (t & 15) * 4;
      ushort4 o;
      o.x = f2b(td[h4 + 0][d]); o.y = f2b(td[h4 + 1][d]);
      o.z = f2b(td[h4 + 2][d]); o.w = f2b(td[h4 + 3][d]);
      *(ushort4*)(dst + (size_t)(n * 64 + d) * 512 + h0 + h4) = o;
    }
  } else {
    #pragma unroll
    for (int i = 0; i < 4; ++i) {
      int f4 = tile * 1024 + i * 256 + t;
      float4 v = ((const float4*)src)[f4];
      ushort4 o; o.x = f2b(v.x); o.y = f2b(v.y); o.z = f2b(v.z); o.w = f2b(v.w);
      ((ushort4*)dst)[f4] = o;
    }
  }
}

// ---------------------------------------------------------------------------
// m97-style MFMA GEMM: C[m,c] = epi( sum_k A[m,k]*BT[c,k] + bias[c] ... )
// 128x128 tile / block (4 waves, each a 64x64 quadrant, 4x4 16x16x32 MFMA).
// K-loop BK=64: global_load_lds(16B) staging of A/BT tiles into XOR-swizzled
// LDS ([row][8 chunks of 16B], chunk_phys = chunk_log ^ (row&7) -> ds_read_b128
// spreads over all 8 bank groups). Epilogue: LDS round-trip -> 16B stores.
// ---------------------------------------------------------------------------
__global__ __launch_bounds__(256) void gemm_mfma(
    const unsigned short* __restrict__ A, const unsigned short* __restrict__ BT,
    const float* __restrict__ bias, const float* __restrict__ cb2,
    const float* __restrict__ pb2, const float* __restrict__ resf,
    const unsigned short* __restrict__ res16,
    void* __restrict__ C1v, unsigned short* __restrict__ C2, int mode)
{
  __shared__ __align__(16) char SMEM[34816];
  unsigned short* As = (unsigned short*)SMEM;          // [128][64] bf16, 16 KB
  unsigned short* Bs = (unsigned short*)(SMEM + 16384);// [128][64] bf16, 16 KB

  const int t = threadIdx.x;
  const int w = t >> 6, lane = t & 63;
  const int l15 = lane & 15, quad = lane >> 4;
  const int r0 = blockIdx.y * 128;
  const int c0 = blockIdx.x * 128;
  const int wm = (w >> 1) * 64, wc = (w & 1) * 64;

  f32x4 acc[4][4];
  #pragma unroll
  for (int sr = 0; sr < 4; ++sr)
    #pragma unroll
    for (int sc = 0; sc < 4; ++sc) acc[sr][sc] = (f32x4){0.f, 0.f, 0.f, 0.f};

  const int sub = lane >> 3;          // row within an 8-row staging slab
  const int g   = (lane & 7) ^ sub;   // logical 16B chunk for swizzled store

  for (int k0 = 0; k0 < 512; k0 += 64) {
    __syncthreads();   // previous iteration's ds_reads done before overwrite
    #pragma unroll
    for (int i = 0; i < 4; ++i) {
      int rowb = w * 32 + i * 8;      // wave-uniform slab base
      gl_lds16(A  + (size_t)(r0 + rowb + sub) * 512 + k0 + g * 8, As + rowb * 64);
      gl_lds16(BT + (size_t)(c0 + rowb + sub) * 512 + k0 + g * 8, Bs + rowb * 64);
    }
    __syncthreads();   // drains vmcnt -> staged data visible

    #pragma unroll
    for (int kk = 0; kk < 2; ++kk) {
      bf16x8 af[4], bf[4];
      #pragma unroll
      for (int s = 0; s < 4; ++s) {
        int ar = wm + s * 16 + l15;
        af[s] = *(const bf16x8*)(As + ar * 64 + (((quad + 4 * kk) ^ (ar & 7)) << 3));
        int br = wc + s * 16 + l15;
        bf[s] = *(const bf16x8*)(Bs + br * 64 + (((quad + 4 * kk) ^ (br & 7)) << 3));
      }
      #pragma unroll
      for (int sr = 0; sr < 4; ++sr)
        #pragma unroll
        for (int sc = 0; sc < 4; ++sc)
          acc[sr][sc] = __builtin_amdgcn_mfma_f32_16x16x32_bf16(
              af[sr], bf[sc], acc[sr][sc], 0, 0, 0);
    }
  }

  __syncthreads();     // staging area dead; reuse SMEM for epilogue

  unsigned short* C1u = (unsigned short*)C1v;
  float* C1f = (float*)C1v;

  if (mode == MODE_F32RES) {
    // fp32 half-tiles [128][68]: wave (w&1)==h owns columns h*64..h*64+63
    float* LDf = (float*)SMEM;
    #pragma unroll
    for (int h = 0; h < 2; ++h) {
      if ((w & 1) == h) {
        #pragma unroll
        for (int sc = 0; sc < 4; ++sc) {
          int cl = sc * 16 + l15;            // 0..63 within half
          float bia = bias[c0 + h * 64 + cl];
          #pragma unroll
          for (int sr = 0; sr < 4; ++sr)
            #pragma unroll
            for (int r = 0; r < 4; ++r) {
              int ml = wm + sr * 16 + quad * 4 + r;
              LDf[ml * 68 + cl] = acc[sr][sc][r] + bia;
            }
        }
      }
      __syncthreads();
      int row = t >> 1, m = r0 + row;
      #pragma unroll
      for (int j = 0; j < 8; ++j) {
        int col = (t & 1) * 32 + j * 4;
        float4 vv = *(const float4*)(LDf + row * 68 + col);
        size_t gofs = (size_t)m * 512 + c0 + h * 64 + col;
        if (resf) {
          float4 rr = *(const float4*)(resf + gofs);
          vv.x += rr.x; vv.y += rr.y; vv.z += rr.z; vv.w += rr.w;
        } else if (res16) {
          ushort4 rv = *(const ushort4*)(res16 + gofs);
          vv.x += b2f(rv.x); vv.y += b2f(rv.y); vv.z += b2f(rv.z); vv.w += b2f(rv.w);
        }
        *(float4*)(C1f + gofs) = vv;
      }
      __syncthreads();
    }
  } else {
    // bf16 tile [128][136] (136: 16B-aligned rows, bank-spread)
    unsigned short* LDb = (unsigned short*)SMEM;
    const int passes = (mode == MODE_QDUAL) ? 2 : 1;
    for (int p = 0; p < passes; ++p) {
      #pragma unroll
      for (int sc = 0; sc < 4; ++sc) {
        int cl = wc + sc * 16 + l15;
        int c = c0 + cl;
        float bia = bias[c];
        if (mode == MODE_QDUAL) bia += (p == 0) ? cb2[c] : pb2[c];
        #pragma unroll
        for (int sr = 0; sr < 4; ++sr)
          #pragma unroll
          for (int r = 0; r < 4; ++r) {
            int ml = wm + sr * 16 + quad * 4 + r;
            float v = acc[sr][sc][r] + bia;
            if (mode == MODE_GELU)
              v = 0.5f * v * (1.0f + erff(v * 0.70710678118654752f));
            if (mode == MODE_VT) LDb[cl * 136 + ml] = f2b(v);
            else                 LDb[ml * 136 + cl] = f2b(v);
          }
      }
      __syncthreads();
      int row = t >> 1;
      #pragma unroll
      for (int j = 0; j < 8; ++j) {
        int col = (t & 1) * 64 + j * 8;
        int4 val = *(const int4*)(LDb + row * 136 + col);
        unsigned short* dst;
        if (mode == MODE_VT) {
          int c = c0 + row, n = c >> 6, d = c & 63;
          int m = r0 + col, bb = m >> 11, l = m & 2047;
          dst = C1u + ((size_t)(bb * NH + n) * DH + d) * LSEQ + l;
        } else if (mode == MODE_RE) {
          int m = r0 + row;
          int c = c0 + col, n = c >> 6, d = c & 63;
          dst = C1u + ((size_t)n * LSEQ + (LSEQ - 1 - m)) * DH + d;
        } else if (mode == MODE_GELU) {
          dst = C1u + (size_t)(r0 + row) * 512 + c0 + col;
        } else { // QDUAL / KV
          int m = r0 + row, bb = m >> 11, l = m & 2047;
          int c = c0 + col, n = c >> 6, d = c & 63;
          dst = ((p == 0) ? C1u : C2) + ((size_t)(bb * NH + n) * LSEQ + l) * DH + d;
        }
        *(int4*)dst = val;
      }
      if (p + 1 < passes) __syncthreads();
    }
  }
}

// ---------------------------------------------------------------------------
// MFMA flash attention (R3/R4-proven, unchanged; writes bf16)
// ---------------------------------------------------------------------------
__global__ __launch_bounds__(256, 2) void attn_mfma(
    const unsigned short* __restrict__ qcb, const unsigned short* __restrict__ qpb,
    const unsigned short* __restrict__ kbb, const unsigned short* __restrict__ vtb,
    const unsigned short* __restrict__ rebb, unsigned short* __restrict__ outb)
{
  __shared__ __align__(16) unsigned short Ks[64 * 72];
  __shared__ __align__(16) unsigned short Vts[64 * 72];
  __shared__ __align__(16) unsigned short Res[128 * 72];
  __shared__ __align__(16) unsigned short Tb[4 * 16 * 84];
  __shared__ __align__(16) unsigned short Pb[4 * 16 * 72];

  const int t = threadIdx.x;
  const int bn = blockIdx.x;
  const int b = bn >> 3, n = bn & 7;
  const int ib = 31 - blockIdx.y;
  const int i0 = ib * 64;
  const int w = t >> 6;
  const int lane = t & 63;
  const int l15 = lane & 15, quad = lane >> 4;

  bf16x8 qcf[2], qpf[2];
  {
    size_t base = ((size_t)bn * LSEQ + i0 + 16 * w + l15) * DH + quad * 8;
    qcf[0] = *(const bf16x8*)(qcb + base);
    qcf[1] = *(const bf16x8*)(qcb + base + 32);
    qpf[0] = *(const bf16x8*)(qpb + base);
    qpf[1] = *(const bf16x8*)(qpb + base + 32);
  }

  f32x4 Of[4];
  #pragma unroll
  for (int s = 0; s < 4; ++s) Of[s] = (f32x4){0.f, 0.f, 0.f, 0.f};
  float m_r[4] = {NEGBIG, NEGBIG, NEGBIG, NEGBIG};
  float l_r[4] = {0.f, 0.f, 0.f, 0.f};

  unsigned short* Tw = Tb + w * 16 * 84;
  unsigned short* Pw = Pb + w * 16 * 72;
  const int Ibase = i0 + 16 * w;
  const int nt = ib + 1;

  for (int tt = 0; tt < nt; ++tt) {
    const int j0 = tt * 64;
    const int db = i0 - j0;
    __syncthreads();
    {
      int r = t >> 2, gl = t & 3;
      int phys = (gl ^ (r & 3)) * 16;
      const int4* sk_ = (const int4*)(kbb + ((size_t)bn * LSEQ + j0 + r) * DH + gl * 16);
      int4 a0 = sk_[0], a1 = sk_[1];
      unsigned short* dk = Ks + r * 72 + phys;
      *(int4*)(dk) = a0; *(int4*)(dk + 8) = a1;
      const int4* sv_ = (const int4*)(vtb + ((size_t)bn * DH + r) * LSEQ + j0 + gl * 16);
      int4 b0 = sv_[0], b1 = sv_[1];
      unsigned short* dv = Vts + r * 72 + phys;
      *(int4*)(dv) = b0; *(int4*)(dv + 8) = b1;
    }
    {
      int r = t >> 1, h = t & 1;
      int dist = db - 63 + r;
      #pragma unroll
      for (int gi = 0; gi < 2; ++gi) {
        int gl = h * 2 + gi;
        unsigned short* dr = Res + r * 72 + ((gl ^ (r & 3)) * 16);
        if (dist >= 0 && dist < LSEQ) {
          const int4* sr = (const int4*)(rebb + ((size_t)n * LSEQ + dist) * DH + gl * 16);
          *(int4*)(dr) = sr[0]; *(int4*)(dr + 8) = sr[1];
        } else {
          int4 z = {0, 0, 0, 0};
          *(int4*)(dr) = z; *(int4*)(dr + 8) = z;
        }
      }
    }
    __syncthreads();

    f32x4 Sf[4];
    #pragma unroll
    for (int s = 0; s < 4; ++s) {
      f32x4 acc = {0.f, 0.f, 0.f, 0.f};
      int row = 16 * s + l15;
      #pragma unroll
      for (int kk = 0; kk < 2; ++kk) {
        int g = (quad >> 1) + 2 * kk;
        bf16x8 bfr = *(const bf16x8*)(Ks + row * 72 + ((g ^ (row & 3)) * 16) + (quad & 1) * 8);
        acc = __builtin_amdgcn_mfma_f32_16x16x32_bf16(qcf[kk], bfr, acc, 0, 0, 0);
      }
      Sf[s] = acc;
    }
    #pragma unroll
    for (int s = 0; s < 5; ++s) {
      f32x4 acc = {0.f, 0.f, 0.f, 0.f};
      int row = 16 * w + 16 * s + l15;
      #pragma unroll
      for (int kk = 0; kk < 2; ++kk) {
        int g = (quad >> 1) + 2 * kk;
        bf16x8 bfr = *(const bf16x8*)(Res + row * 72 + ((g ^ (row & 3)) * 16) + (quad & 1) * 8);
        acc = __builtin_amdgcn_mfma_f32_16x16x32_bf16(qpf[kk], bfr, acc, 0, 0, 0);
      }
      #pragma unroll
      for (int r = 0; r < 4; ++r) {
        float val = acc[r];
        float other = __shfl_xor(val, 1, 64);
        if ((lane & 1) == 0) {
          int i = quad * 4 + r;
          unsigned pack = (unsigned)f2b(val) | ((unsigned)f2b(other) << 16);
          *(unsigned*)(Tw + i * 84 + 16 * s + l15) = pack;
        }
      }
    }
    asm volatile("s_waitcnt lgkmcnt(0)" ::: "memory");

    float p_s[4][4];
    float alpha[4];
    {
      float sc[4][4];
      #pragma unroll
      for (int s = 0; s < 4; ++s)
        #pragma unroll
        for (int r = 0; r < 4; ++r) {
          int i = quad * 4 + r;
          float tval = b2f(Tw[i * 84 + 63 + i - 16 * s - l15]);
          float v = (Sf[s][r] + tval) * 0.125f;
          int j = j0 + 16 * s + l15;
          sc[s][r] = (j <= Ibase + i) ? v : NEGBIG;
        }
      #pragma unroll
      for (int r = 0; r < 4; ++r) {
        float mx = fmaxf(fmaxf(sc[0][r], sc[1][r]), fmaxf(sc[2][r], sc[3][r]));
        #pragma unroll
        for (int off = 8; off >= 1; off >>= 1) mx = fmaxf(mx, __shfl_xor(mx, off, 64));
        float mn = fmaxf(m_r[r], mx);
        alpha[r] = __expf(m_r[r] - mn);
        m_r[r] = mn;
        float rs = 0.f;
        #pragma unroll
        for (int s = 0; s < 4; ++s) {
          float p = __expf(sc[s][r] - mn);
          p_s[s][r] = p; rs += p;
        }
        #pragma unroll
        for (int off = 8; off >= 1; off >>= 1) rs += __shfl_xor(rs, off, 64);
        l_r[r] = l_r[r] * alpha[r] + rs;
      }
      #pragma unroll
      for (int s = 0; s < 4; ++s)
        #pragma unroll
        for (int r = 0; r < 4; ++r) {
          float val = p_s[s][r];
          float other = __shfl_xor(val, 1, 64);
          if ((lane & 1) == 0) {
            int i = quad * 4 + r;
            unsigned pack = (unsigned)f2b(val) | ((unsigned)f2b(other) << 16);
            *(unsigned*)(Pw + i * 72 + ((s ^ (i & 3)) * 16) + l15) = pack;
          }
        }
      #pragma unroll
      for (int s = 0; s < 4; ++s)
        #pragma unroll
        for (int r = 0; r < 4; ++r) Of[s][r] *= alpha[r];
    }
    asm volatile("s_waitcnt lgkmcnt(0)" ::: "memory");

    #pragma unroll
    for (int kk = 0; kk < 2; ++kk) {
      int g = (quad >> 1) + 2 * kk;
      bf16x8 pa = *(const bf16x8*)(Pw + l15 * 72 + ((g ^ (l15 & 3)) * 16) + (quad & 1) * 8);
      #pragma unroll
      for (int s = 0; s < 4; ++s) {
        int d = 16 * s + l15;
        bf16x8 vb8 = *(const bf16x8*)(Vts + d * 72 + ((g ^ (d & 3)) * 16) + (quad & 1) * 8);
        Of[s] = __builtin_amdgcn_mfma_f32_16x16x32_bf16(pa, vb8, Of[s], 0, 0, 0);
      }
    }
  }

  #pragma unroll
  for (int r = 0; r < 4; ++r) {
    float linv = 1.0f / l_r[r];
    int I = Ibase + quad * 4 + r;
    size_t base = ((size_t)b * LSEQ + I) * HDIM + n * DH;
    #pragma unroll
    for (int s = 0; s < 4; ++s)
      outb[base + 16 * s + l15] = f2b(Of[s][r] * linv);
  }
}

// ---------------------------------------------------------------------------
// LayerNorm over last dim (512): outf (fp32) and/or out16 (bf16), nullable
// ---------------------------------------------------------------------------
__global__ __launch_bounds__(256) void ln_kernel(
    const float* __restrict__ xin, const float* __restrict__ w,
    const float* __restrict__ bb, float* __restrict__ outf,
    unsigned short* __restrict__ out16)
{
  __shared__ float red[8];
  const int row = blockIdx.x, t = threadIdx.x;
  const size_t base = (size_t)row * 512;
  float v0 = xin[base + t], v1 = xin[base + t + 256];
  float s = v0 + v1;
  #pragma unroll
  for (int off = 32; off >= 1; off >>= 1) s += __shfl_xor(s, off, 64);
  if ((t & 63) == 0) red[t >> 6] = s;
  __syncthreads();
  float mean = (red[0] + red[1] + red[2] + red[3]) * (1.0f / 512.0f);
  float d0 = v0 - mean, d1 = v1 - mean;
  float s2 = d0 * d0 + d1 * d1;
  #pragma unroll
  for (int off = 32; off >= 1; off >>= 1) s2 += __shfl_xor(s2, off, 64);
  if ((t & 63) == 0) red[4 + (t >> 6)] = s2;
  __syncthreads();
  float var = (red[4] + red[5] + red[6] + red[7]) * (1.0f / 512.0f);
  float inv = 1.0f / sqrtf(var + 1e-12f);
  float o0 = w[t] * d0 * inv + bb[t];
  float o1 = w[t + 256] * d1 * inv + bb[t + 256];
  if (outf)  { outf[base + t] = o0; outf[base + t + 256] = o1; }
  if (out16) { out16[base + t] = f2b(o0); out16[base + t + 256] = f2b(o1); }
}

// ---------------------------------------------------------------------------
extern "C" void kernel_launch(void* const* d_in, const int* in_sizes, int n_in,
                              void* d_out, int out_size, void* d_ws, size_t ws_size,
                              hipStream_t stream)
{
  (void)in_sizes; (void)n_in; (void)out_size; (void)ws_size;
  const float* x   = (const float*)d_in[0];
  const float* pos = (const float*)d_in[1];
  const float* Wq  = (const float*)d_in[2];
  const float* bq  = (const float*)d_in[3];
  const float* Wk  = (const float*)d_in[4];
  const float* bk  = (const float*)d_in[5];
  const float* Wv  = (const float*)d_in[6];
  const float* bv  = (const float*)d_in[7];
  const float* Wr  = (const float*)d_in[8];
  const float* br  = (const float*)d_in[9];
  const float* cbv = (const float*)d_in[10];
  const float* pbv = (const float*)d_in[11];
  const float* Wc  = (const float*)d_in[12];
  const float* bc  = (const float*)d_in[13];
  const float* W1  = (const float*)d_in[14];
  const float* b1  = (const float*)d_in[15];
  const float* W2  = (const float*)d_in[16];
  const float* b2  = (const float*)d_in[17];
  const float* lnw = (const float*)d_in[18];
  const float* lnb = (const float*)d_in[19];
  char* ws = (char*)d_ws;
  float* outp = (float*)d_out;

  unsigned short* xb   = (unsigned short*)(ws);
  unsigned short* posb = (unsigned short*)(ws + 8388608);
  unsigned short* wT   = (unsigned short*)(ws + 10485760);
  unsigned short* qcb  = (unsigned short*)(ws + 14155776);
  unsigned short* qpb  = (unsigned short*)(ws + 22544384);
  unsigned short* kbb  = (unsigned short*)(ws + 30932992);
  unsigned short* vtb  = (unsigned short*)(ws + 39321600);
  unsigned short* rebb = (unsigned short*)(ws + 47710208);
  unsigned short* WqT = wT;
  unsigned short* WkT = wT + 262144;
  unsigned short* WvT = wT + 2 * 262144;
  unsigned short* WrT = wT + 3 * 262144;
  unsigned short* WcT = wT + 4 * 262144;
  unsigned short* W1T = wT + 5 * 262144;
  unsigned short* W2T = wT + 6 * 262144;
  unsigned short* attnb = (unsigned short*)d_out;
  float*          cpre  = (float*)(ws + 14155776);
  unsigned short* ab16  = (unsigned short*)(ws);
  unsigned short* h1b   = (unsigned short*)(ws + 30932992);
  float*          h2pre = (float*)(ws + 14155776);

  dim3 blk(256);
  dim3 g8(4, 64);    // M=8192: 128x128 tiles
  dim3 g2(4, 16);    // M=2048

  conv_f32_bf16<<<4096, blk, 0, stream>>>(x, xb, 1048576);
  conv_f32_bf16<<<1024, blk, 0, stream>>>(pos, posb, 262144);
  conv_weights<<<dim3(64, 7), blk, 0, stream>>>(Wq, Wk, Wv, Wr, Wc, W1, W2, wT);

  gemm_mfma<<<g8, blk, 0, stream>>>(xb, WqT, bq, cbv, pbv, nullptr, nullptr,
                                    qcb, qpb, MODE_QDUAL);
  gemm_mfma<<<g8, blk, 0, stream>>>(xb, WkT, bk, nullptr, nullptr, nullptr, nullptr,
                                    kbb, nullptr, MODE_KV);
  gemm_mfma<<<g8, blk, 0, stream>>>(xb, WvT, bv, nullptr, nullptr, nullptr, nullptr,
                                    vtb, nullptr, MODE_VT);
  gemm_mfma<<<g2, blk, 0, stream>>>(posb, WrT, br, nullptr, nullptr, nullptr, nullptr,
                                    rebb, nullptr, MODE_RE);

  attn_mfma<<<dim3(32, 32), blk, 0, stream>>>(qcb, qpb, kbb, vtb, rebb, attnb);

  gemm_mfma<<<g8, blk, 0, stream>>>(attnb, WcT, bc, nullptr, nullptr, x, nullptr,
                                    cpre, nullptr, MODE_F32RES);
  ln_kernel<<<8192, blk, 0, stream>>>(cpre, lnw, lnb, nullptr, ab16);
  gemm_mfma<<<g8, blk, 0, stream>>>(ab16, W1T, b1, nullptr, nullptr, nullptr, nullptr,
                                    h1b, nullptr, MODE_GELU);
  gemm_mfma<<<g8, blk, 0, stream>>>(h1b, W2T, b2, nullptr, nullptr, nullptr, ab16,
                                    h2pre, nullptr, MODE_F32RES);
  ln_kernel<<<8192, blk, 0, stream>>>(h2pre, lnw, lnb, outp, nullptr);
}

// Round 6
// 398.502 us; speedup vs baseline: 9.0377x; 1.0938x over previous
//
#include <hip/hip_runtime.h>
#include <math.h>

#define HDIM 512
#define LSEQ 2048
#define NH 8
#define DH 64
#define NEGBIG (-3.0e38f)

#define MODE_QDUAL  0
#define MODE_KV     1
#define MODE_VT     2
#define MODE_RE     3
#define MODE_F32RES 4
#define MODE_GELU   5

typedef short bf16x8 __attribute__((ext_vector_type(8)));
typedef float f32x4 __attribute__((ext_vector_type(4)));

__device__ __forceinline__ unsigned short f2b(float f) {
  union { float f; unsigned u; } x; x.f = f;
  unsigned r = x.u + 0x7FFF + ((x.u >> 16) & 1);
  return (unsigned short)(r >> 16);
}
__device__ __forceinline__ float b2f(unsigned short u) {
  union { unsigned u; float f; } x; x.u = ((unsigned)u) << 16;
  return x.f;
}

// async global->LDS, 16B per lane; LDS dest = wave-uniform base + lane*16
__device__ __forceinline__ void gl_lds16(const void* g, void* l) {
  __builtin_amdgcn_global_load_lds(
      (const __attribute__((address_space(1))) void*)g,
      (__attribute__((address_space(3))) void*)l, 16, 0, 0);
}

// ---------------------------------------------------------------------------
// fp32 -> bf16 vector convert (x, pos_enc)
// ---------------------------------------------------------------------------
__global__ __launch_bounds__(256) void conv_f32_bf16(
    const float* __restrict__ in, unsigned short* __restrict__ out, int n4)
{
  int idx = blockIdx.x * 256 + threadIdx.x;
  if (idx < n4) {
    float4 v = ((const float4*)in)[idx];
    ushort4 o; o.x = f2b(v.x); o.y = f2b(v.y); o.z = f2b(v.z); o.w = f2b(v.w);
    ((ushort4*)out)[idx] = o;
  }
}

// ---------------------------------------------------------------------------
// Weight prep: widx 0..3 (Wq,Wk,Wv,Wr [n,h,d] -> bf16 [n*64+d][h] B^T form),
//              widx 4..6 (Wc,W1,W2 [c,k] row-major -> bf16 straight convert)
// ---------------------------------------------------------------------------
__global__ __launch_bounds__(256) void conv_weights(
    const float* __restrict__ Wq, const float* __restrict__ Wk,
    const float* __restrict__ Wv, const float* __restrict__ Wr,
    const float* __restrict__ Wc, const float* __restrict__ W1,
    const float* __restrict__ W2, unsigned short* __restrict__ wT)
{
  const int widx = blockIdx.y;
  const float* src = (widx == 0) ? Wq : (widx == 1) ? Wk : (widx == 2) ? Wv :
                     (widx == 3) ? Wr : (widx == 4) ? Wc : (widx == 5) ? W1 : W2;
  unsigned short* dst = wT + (size_t)widx * 262144;
  const int t = threadIdx.x;
  const int tile = blockIdx.x;

  if (widx < 4) {
    __shared__ float td[64][65];
    const int h0 = (tile >> 3) * 64;
    const int n  = tile & 7;
    #pragma unroll
    for (int it = 0; it < 4; ++it) {
      int row = it * 16 + (t >> 4), dc = (t & 15) * 4;
      float4 v = *(const float4*)(src + (size_t)n * 32768 + (size_t)(h0 + row) * 64 + dc);
      td[row][dc] = v.x; td[row][dc + 1] = v.y; td[row][dc + 2] = v.z; td[row][dc + 3] = v.w;
    }
    __syncthreads();
    #pragma unroll
    for (int it = 0; it < 4; ++it) {
      int d = it * 16 + (t >> 4), h4 = (t & 15) * 4;
      ushort4 o;
      o.x = f2b(td[h4 + 0][d]); o.y = f2b(td[h4 + 1][d]);
      o.z = f2b(td[h4 + 2][d]); o.w = f2b(td[h4 + 3][d]);
      *(ushort4*)(dst + (size_t)(n * 64 + d) * 512 + h0 + h4) = o;
    }
  } else {
    #pragma unroll
    for (int i = 0; i < 4; ++i) {
      int f4 = tile * 1024 + i * 256 + t;
      float4 v = ((const float4*)src)[f4];
      ushort4 o; o.x = f2b(v.x); o.y = f2b(v.y); o.z = f2b(v.z); o.w = f2b(v.w);
      ((ushort4*)dst)[f4] = o;
    }
  }
}

// ---------------------------------------------------------------------------
// MFMA GEMM, 128x64 tile / block (512 blocks -> 2/CU for cross-block overlap).
// 4 waves, each 64x32 (4x2 16x16x32 subtiles). BK=64 via global_load_lds(16B)
// into XOR-swizzled LDS. Epilogue via LDS roundtrip -> coalesced 16B stores.
// MODE_QDUAL additionally scales by 0.125 (attention 1/sqrt(D) folded in).
// ---------------------------------------------------------------------------
__global__ __launch_bounds__(256) void gemm_mfma(
    const unsigned short* __restrict__ A, const unsigned short* __restrict__ BT,
    const float* __restrict__ bias, const float* __restrict__ cb2,
    const float* __restrict__ pb2, const float* __restrict__ resf,
    const unsigned short* __restrict__ res16,
    void* __restrict__ C1v, unsigned short* __restrict__ C2, int mode)
{
  __shared__ __align__(16) char SMEM[24576];
  unsigned short* As = (unsigned short*)SMEM;            // [128][64] 16 KB
  unsigned short* Bs = (unsigned short*)(SMEM + 16384);  // [64][64]   8 KB

  const int t = threadIdx.x;
  const int w = t >> 6, lane = t & 63;
  const int l15 = lane & 15, quad = lane >> 4;
  const int r0 = blockIdx.y * 128;
  const int c0 = blockIdx.x * 64;
  const int wm = (w >> 1) * 64, wc = (w & 1) * 32;

  f32x4 acc[4][2];
  #pragma unroll
  for (int sr = 0; sr < 4; ++sr)
    #pragma unroll
    for (int sc = 0; sc < 2; ++sc) acc[sr][sc] = (f32x4){0.f, 0.f, 0.f, 0.f};

  const int sub = lane >> 3;
  const int g   = (lane & 7) ^ sub;

  for (int k0 = 0; k0 < 512; k0 += 64) {
    __syncthreads();
    #pragma unroll
    for (int i = 0; i < 4; ++i) {
      int rowb = w * 32 + i * 8;
      gl_lds16(A + (size_t)(r0 + rowb + sub) * 512 + k0 + g * 8, As + rowb * 64);
    }
    #pragma unroll
    for (int i = 0; i < 2; ++i) {
      int rowb = w * 16 + i * 8;
      gl_lds16(BT + (size_t)(c0 + rowb + sub) * 512 + k0 + g * 8, Bs + rowb * 64);
    }
    __syncthreads();

    #pragma unroll
    for (int kk = 0; kk < 2; ++kk) {
      bf16x8 af[4], bf[2];
      #pragma unroll
      for (int s = 0; s < 4; ++s) {
        int ar = wm + s * 16 + l15;
        af[s] = *(const bf16x8*)(As + ar * 64 + (((quad + 4 * kk) ^ (ar & 7)) << 3));
      }
      #pragma unroll
      for (int s = 0; s < 2; ++s) {
        int br = wc + s * 16 + l15;
        bf[s] = *(const bf16x8*)(Bs + br * 64 + (((quad + 4 * kk) ^ (br & 7)) << 3));
      }
      #pragma unroll
      for (int sr = 0; sr < 4; ++sr)
        #pragma unroll
        for (int sc = 0; sc < 2; ++sc)
          acc[sr][sc] = __builtin_amdgcn_mfma_f32_16x16x32_bf16(
              af[sr], bf[sc], acc[sr][sc], 0, 0, 0);
    }
  }

  __syncthreads();

  unsigned short* C1u = (unsigned short*)C1v;
  float* C1f = (float*)C1v;

  if (mode == MODE_F32RES) {
    float* LDf = (float*)SMEM;                 // [64][68] per half
    #pragma unroll
    for (int h = 0; h < 2; ++h) {
      if ((w >> 1) == h) {
        #pragma unroll
        for (int sc = 0; sc < 2; ++sc) {
          int cl = wc + sc * 16 + l15;
          float bia = bias[c0 + cl];
          #pragma unroll
          for (int sr = 0; sr < 4; ++sr)
            #pragma unroll
            for (int r = 0; r < 4; ++r) {
              int ml = sr * 16 + quad * 4 + r;
              LDf[ml * 68 + cl] = acc[sr][sc][r] + bia;
            }
        }
      }
      __syncthreads();
      int row = t >> 2, m = r0 + h * 64 + row;
      #pragma unroll
      for (int j = 0; j < 4; ++j) {
        int col = (t & 3) * 16 + j * 4;
        float4 vv = *(const float4*)(LDf + row * 68 + col);
        size_t gofs = (size_t)m * 512 + c0 + col;
        if (resf) {
          float4 rr = *(const float4*)(resf + gofs);
          vv.x += rr.x; vv.y += rr.y; vv.z += rr.z; vv.w += rr.w;
        } else if (res16) {
          ushort4 rv = *(const ushort4*)(res16 + gofs);
          vv.x += b2f(rv.x); vv.y += b2f(rv.y); vv.z += b2f(rv.z); vv.w += b2f(rv.w);
        }
        *(float4*)(C1f + gofs) = vv;
      }
      __syncthreads();
    }
  } else if (mode == MODE_VT) {
    unsigned short* LDb = (unsigned short*)SMEM;   // [64][136]
    #pragma unroll
    for (int sc = 0; sc < 2; ++sc) {
      int cl = wc + sc * 16 + l15;
      float bia = bias[c0 + cl];
      #pragma unroll
      for (int sr = 0; sr < 4; ++sr)
        #pragma unroll
        for (int r = 0; r < 4; ++r) {
          int ml = wm + sr * 16 + quad * 4 + r;
          LDb[cl * 136 + ml] = f2b(acc[sr][sc][r] + bia);
        }
    }
    __syncthreads();
    int row = t >> 2;                 // c-local 0..63
    int c = c0 + row, n = c >> 6, d = c & 63;
    #pragma unroll
    for (int j = 0; j < 4; ++j) {
      int mcol = (t & 3) * 32 + j * 8;
      int4 val = *(const int4*)(LDb + row * 136 + mcol);
      int m = r0 + mcol, bb = m >> 11, l = m & 2047;
      *(int4*)(C1u + ((size_t)(bb * NH + n) * DH + d) * LSEQ + l) = val;
    }
  } else {
    unsigned short* LDb = (unsigned short*)SMEM;   // [128][72]
    const int passes = (mode == MODE_QDUAL) ? 2 : 1;
    for (int p = 0; p < passes; ++p) {
      #pragma unroll
      for (int sc = 0; sc < 2; ++sc) {
        int cl = wc + sc * 16 + l15;
        int c = c0 + cl;
        float bia = bias[c];
        float ex = (mode == MODE_QDUAL) ? ((p == 0) ? cb2[c] : pb2[c]) : 0.f;
        #pragma unroll
        for (int sr = 0; sr < 4; ++sr)
          #pragma unroll
          for (int r = 0; r < 4; ++r) {
            int ml = wm + sr * 16 + quad * 4 + r;
            float v = acc[sr][sc][r] + bia;
            if (mode == MODE_QDUAL) v = (v + ex) * 0.125f;   // fold 1/sqrt(D)
            if (mode == MODE_GELU)
              v = 0.5f * v * (1.0f + erff(v * 0.70710678118654752f));
            LDb[ml * 72 + cl] = f2b(v);
          }
      }
      __syncthreads();
      int row = t >> 1;
      #pragma unroll
      for (int j = 0; j < 4; ++j) {
        int col = (t & 1) * 32 + j * 8;
        int4 val = *(const int4*)(LDb + row * 72 + col);
        unsigned short* dst;
        int c = c0 + col, n = c >> 6, d = c & 63;
        if (mode == MODE_RE) {
          int m = r0 + row;
          dst = C1u + ((size_t)n * LSEQ + (LSEQ - 1 - m)) * DH + d;
        } else if (mode == MODE_GELU) {
          dst = C1u + (size_t)(r0 + row) * 512 + c0 + col;
        } else { // QDUAL / KV
          int m = r0 + row, bb = m >> 11, l = m & 2047;
          dst = ((p == 0) ? C1u : C2) + ((size_t)(bb * NH + n) * LSEQ + l) * DH + d;
        }
        *(int4*)dst = val;
      }
      if (p + 1 < passes) __syncthreads();
    }
  }
}

// ---------------------------------------------------------------------------
// MFMA flash attention, Transformer-XL relative positions.
// R6: max-free softmax (scores pre-scaled by 0.125 in q-projection; |s|<~2 so
// exp is safe), per-lane l accumulated and reduced once; T/P LDS aliased
// (wave-private, in-order DS) -> 47.6 KB -> 3 blocks/CU; K/V/Res prefetched
// to registers before the barrier.
// ---------------------------------------------------------------------------
__global__ __launch_bounds__(256, 3) void attn_mfma(
    const unsigned short* __restrict__ qcb, const unsigned short* __restrict__ qpb,
    const unsigned short* __restrict__ kbb, const unsigned short* __restrict__ vtb,
    const unsigned short* __restrict__ rebb, unsigned short* __restrict__ outb)
{
  __shared__ __align__(16) unsigned short Ks[64 * 72];
  __shared__ __align__(16) unsigned short Vts[64 * 72];
  __shared__ __align__(16) unsigned short Res[128 * 72];
  __shared__ __align__(16) unsigned short TPb[4 * 16 * 84];   // T(84) / P(72) aliased

  const int t = threadIdx.x;
  const int bn = blockIdx.x;
  const int b = bn >> 3, n = bn & 7;
  const int ib = 31 - blockIdx.y;       // heavy blocks dispatched first
  const int i0 = ib * 64;
  const int w = t >> 6;
  const int lane = t & 63;
  const int l15 = lane & 15, quad = lane >> 4;

  bf16x8 qcf[2], qpf[2];
  {
    size_t base = ((size_t)bn * LSEQ + i0 + 16 * w + l15) * DH + quad * 8;
    qcf[0] = *(const bf16x8*)(qcb + base);
    qcf[1] = *(const bf16x8*)(qcb + base + 32);
    qpf[0] = *(const bf16x8*)(qpb + base);
    qpf[1] = *(const bf16x8*)(qpb + base + 32);
  }

  f32x4 Of[4];
  #pragma unroll
  for (int s = 0; s < 4; ++s) Of[s] = (f32x4){0.f, 0.f, 0.f, 0.f};
  float lsum[4] = {0.f, 0.f, 0.f, 0.f};

  unsigned short* Tw = TPb + w * 1344;   // stride 84 (T) / 72 (P), aliased
  const int Ibase = i0 + 16 * w;
  const int nt = ib + 1;

  // staging index precompute
  const int r2 = t >> 2, gl2 = t & 3;
  const int r1 = t >> 1, h1 = t & 1;

  for (int tt = 0; tt < nt; ++tt) {
    const int j0 = tt * 64;
    const int db = i0 - j0;

    // ---- prefetch K/V/Res into registers (overlaps other waves' compute) ----
    const int4* skp = (const int4*)(kbb + ((size_t)bn * LSEQ + j0 + r2) * DH + gl2 * 16);
    int4 ka0 = skp[0], ka1 = skp[1];
    const int4* svp = (const int4*)(vtb + ((size_t)bn * DH + r2) * LSEQ + j0 + gl2 * 16);
    int4 va0 = svp[0], va1 = svp[1];
    int dist = db - 63 + r1;
    int4 ra[2][2];
    #pragma unroll
    for (int gi = 0; gi < 2; ++gi) {
      if (dist >= 0 && dist < LSEQ) {
        const int4* srp = (const int4*)(rebb + ((size_t)n * LSEQ + dist) * DH + (h1 * 2 + gi) * 16);
        ra[gi][0] = srp[0]; ra[gi][1] = srp[1];
      } else {
        int4 z = {0, 0, 0, 0};
        ra[gi][0] = z; ra[gi][1] = z;
      }
    }
    __syncthreads();   // previous tile's LDS reads complete
    {
      unsigned short* dk = Ks + r2 * 72 + ((gl2 ^ (r2 & 3)) * 16);
      *(int4*)(dk) = ka0; *(int4*)(dk + 8) = ka1;
      unsigned short* dv = Vts + r2 * 72 + ((gl2 ^ (r2 & 3)) * 16);
      *(int4*)(dv) = va0; *(int4*)(dv + 8) = va1;
      #pragma unroll
      for (int gi = 0; gi < 2; ++gi) {
        int gl = h1 * 2 + gi;
        unsigned short* dr = Res + r1 * 72 + ((gl ^ (r1 & 3)) * 16);
        *(int4*)(dr) = ra[gi][0]; *(int4*)(dr + 8) = ra[gi][1];
      }
    }
    __syncthreads();

    // ---- content scores ----
    f32x4 Sf[4];
    #pragma unroll
    for (int s = 0; s < 4; ++s) {
      f32x4 acc = {0.f, 0.f, 0.f, 0.f};
      int row = 16 * s + l15;
      #pragma unroll
      for (int kk = 0; kk < 2; ++kk) {
        int g = (quad >> 1) + 2 * kk;
        bf16x8 bfr = *(const bf16x8*)(Ks + row * 72 + ((g ^ (row & 3)) * 16) + (quad & 1) * 8);
        acc = __builtin_amdgcn_mfma_f32_16x16x32_bf16(qcf[kk], bfr, acc, 0, 0, 0);
      }
      Sf[s] = acc;
    }
    // ---- positional T = qp . re_band^T -> Tw ----
    #pragma unroll
    for (int s = 0; s < 5; ++s) {
      f32x4 acc = {0.f, 0.f, 0.f, 0.f};
      int row = 16 * w + 16 * s + l15;
      #pragma unroll
      for (int kk = 0; kk < 2; ++kk) {
        int g = (quad >> 1) + 2 * kk;
        bf16x8 bfr = *(const bf16x8*)(Res + row * 72 + ((g ^ (row & 3)) * 16) + (quad & 1) * 8);
        acc = __builtin_amdgcn_mfma_f32_16x16x32_bf16(qpf[kk], bfr, acc, 0, 0, 0);
      }
      #pragma unroll
      for (int r = 0; r < 4; ++r) {
        float val = acc[r];
        float other = __shfl_xor(val, 1, 64);
        if ((lane & 1) == 0) {
          int i = quad * 4 + r;
          unsigned pack = (unsigned)f2b(val) | ((unsigned)f2b(other) << 16);
          *(unsigned*)(Tw + i * 84 + 16 * s + l15) = pack;
        }
      }
    }
    asm volatile("s_waitcnt lgkmcnt(0)" ::: "memory");

    // ---- max-free softmax ----
    float p_s[4][4];
    #pragma unroll
    for (int s = 0; s < 4; ++s)
      #pragma unroll
      for (int r = 0; r < 4; ++r) {
        int i = quad * 4 + r;
        float tval = b2f(Tw[i * 84 + 63 + i - 16 * s - l15]);
        float v = Sf[s][r] + tval;
        int j = j0 + 16 * s + l15;
        float p = (j <= Ibase + i) ? __expf(v) : 0.0f;
        p_s[s][r] = p;
        lsum[r] += p;
      }
    // pack P (bf16 pairs) into aliased buffer (stride 72, col-swizzled)
    #pragma unroll
    for (int s = 0; s < 4; ++s)
      #pragma unroll
      for (int r = 0; r < 4; ++r) {
        float val = p_s[s][r];
        float other = __shfl_xor(val, 1, 64);
        if ((lane & 1) == 0) {
          int i = quad * 4 + r;
          unsigned pack = (unsigned)f2b(val) | ((unsigned)f2b(other) << 16);
          *(unsigned*)(Tw + i * 72 + ((s ^ (i & 3)) * 16) + l15) = pack;
        }
      }
    asm volatile("s_waitcnt lgkmcnt(0)" ::: "memory");

    // ---- PV: O += P . V ----
    #pragma unroll
    for (int kk = 0; kk < 2; ++kk) {
      int g = (quad >> 1) + 2 * kk;
      bf16x8 pa = *(const bf16x8*)(Tw + l15 * 72 + ((g ^ (l15 & 3)) * 16) + (quad & 1) * 8);
      #pragma unroll
      for (int s = 0; s < 4; ++s) {
        int d = 16 * s + l15;
        bf16x8 vb8 = *(const bf16x8*)(Vts + d * 72 + ((g ^ (d & 3)) * 16) + (quad & 1) * 8);
        Of[s] = __builtin_amdgcn_mfma_f32_16x16x32_bf16(pa, vb8, Of[s], 0, 0, 0);
      }
    }
  }

  // ---- epilogue: reduce l across the 16-lane row group, write bf16 ----
  #pragma unroll
  for (int r = 0; r < 4; ++r) {
    float rs = lsum[r];
    rs += __shfl_xor(rs, 1, 64);
    rs += __shfl_xor(rs, 2, 64);
    rs += __shfl_xor(rs, 4, 64);
    rs += __shfl_xor(rs, 8, 64);
    float linv = 1.0f / rs;
    int I = Ibase + quad * 4 + r;
    size_t base = ((size_t)b * LSEQ + I) * HDIM + n * DH;
    #pragma unroll
    for (int s = 0; s < 4; ++s)
      outb[base + 16 * s + l15] = f2b(Of[s][r] * linv);
  }
}

// ---------------------------------------------------------------------------
// LayerNorm over last dim (512): outf (fp32) and/or out16 (bf16), nullable
// ---------------------------------------------------------------------------
__global__ __launch_bounds__(256) void ln_kernel(
    const float* __restrict__ xin, const float* __restrict__ w,
    const float* __restrict__ bb, float* __restrict__ outf,
    unsigned short* __restrict__ out16)
{
  __shared__ float red[8];
  const int row = blockIdx.x, t = threadIdx.x;
  const size_t base = (size_t)row * 512;
  float v0 = xin[base + t], v1 = xin[base + t + 256];
  float s = v0 + v1;
  #pragma unroll
  for (int off = 32; off >= 1; off >>= 1) s += __shfl_xor(s, off, 64);
  if ((t & 63) == 0) red[t >> 6] = s;
  __syncthreads();
  float mean = (red[0] + red[1] + red[2] + red[3]) * (1.0f / 512.0f);
  float d0 = v0 - mean, d1 = v1 - mean;
  float s2 = d0 * d0 + d1 * d1;
  #pragma unroll
  for (int off = 32; off >= 1; off >>= 1) s2 += __shfl_xor(s2, off, 64);
  if ((t & 63) == 0) red[4 + (t >> 6)] = s2;
  __syncthreads();
  float var = (red[4] + red[5] + red[6] + red[7]) * (1.0f / 512.0f);
  float inv = 1.0f / sqrtf(var + 1e-12f);
  float o0 = w[t] * d0 * inv + bb[t];
  float o1 = w[t + 256] * d1 * inv + bb[t + 256];
  if (outf)  { outf[base + t] = o0; outf[base + t + 256] = o1; }
  if (out16) { out16[base + t] = f2b(o0); out16[base + t + 256] = f2b(o1); }
}

// ---------------------------------------------------------------------------
extern "C" void kernel_launch(void* const* d_in, const int* in_sizes, int n_in,
                              void* d_out, int out_size, void* d_ws, size_t ws_size,
                              hipStream_t stream)
{
  (void)in_sizes; (void)n_in; (void)out_size; (void)ws_size;
  const float* x   = (const float*)d_in[0];
  const float* pos = (const float*)d_in[1];
  const float* Wq  = (const float*)d_in[2];
  const float* bq  = (const float*)d_in[3];
  const float* Wk  = (const float*)d_in[4];
  const float* bk  = (const float*)d_in[5];
  const float* Wv  = (const float*)d_in[6];
  const float* bv  = (const float*)d_in[7];
  const float* Wr  = (const float*)d_in[8];
  const float* br  = (const float*)d_in[9];
  const float* cbv = (const float*)d_in[10];
  const float* pbv = (const float*)d_in[11];
  const float* Wc  = (const float*)d_in[12];
  const float* bc  = (const float*)d_in[13];
  const float* W1  = (const float*)d_in[14];
  const float* b1  = (const float*)d_in[15];
  const float* W2  = (const float*)d_in[16];
  const float* b2  = (const float*)d_in[17];
  const float* lnw = (const float*)d_in[18];
  const float* lnb = (const float*)d_in[19];
  char* ws = (char*)d_ws;
  float* outp = (float*)d_out;

  unsigned short* xb   = (unsigned short*)(ws);
  unsigned short* posb = (unsigned short*)(ws + 8388608);
  unsigned short* wT   = (unsigned short*)(ws + 10485760);
  unsigned short* qcb  = (unsigned short*)(ws + 14155776);
  unsigned short* qpb  = (unsigned short*)(ws + 22544384);
  unsigned short* kbb  = (unsigned short*)(ws + 30932992);
  unsigned short* vtb  = (unsigned short*)(ws + 39321600);
  unsigned short* rebb = (unsigned short*)(ws + 47710208);
  unsigned short* WqT = wT;
  unsigned short* WkT = wT + 262144;
  unsigned short* WvT = wT + 2 * 262144;
  unsigned short* WrT = wT + 3 * 262144;
  unsigned short* WcT = wT + 4 * 262144;
  unsigned short* W1T = wT + 5 * 262144;
  unsigned short* W2T = wT + 6 * 262144;
  unsigned short* attnb = (unsigned short*)d_out;
  float*          cpre  = (float*)(ws + 14155776);
  unsigned short* ab16  = (unsigned short*)(ws);
  unsigned short* h1b   = (unsigned short*)(ws + 30932992);
  float*          h2pre = (float*)(ws + 14155776);

  dim3 blk(256);
  dim3 g8(8, 64);    // M=8192: 128x64 tiles -> 512 blocks
  dim3 g2(8, 16);    // M=2048

  conv_f32_bf16<<<4096, blk, 0, stream>>>(x, xb, 1048576);
  conv_f32_bf16<<<1024, blk, 0, stream>>>(pos, posb, 262144);
  conv_weights<<<dim3(64, 7), blk, 0, stream>>>(Wq, Wk, Wv, Wr, Wc, W1, W2, wT);

  gemm_mfma<<<g8, blk, 0, stream>>>(xb, WqT, bq, cbv, pbv, nullptr, nullptr,
                                    qcb, qpb, MODE_QDUAL);
  gemm_mfma<<<g8, blk, 0, stream>>>(xb, WkT, bk, nullptr, nullptr, nullptr, nullptr,
                                    kbb, nullptr, MODE_KV);
  gemm_mfma<<<g8, blk, 0, stream>>>(xb, WvT, bv, nullptr, nullptr, nullptr, nullptr,
                                    vtb, nullptr, MODE_VT);
  gemm_mfma<<<g2, blk, 0, stream>>>(posb, WrT, br, nullptr, nullptr, nullptr, nullptr,
                                    rebb, nullptr, MODE_RE);

  attn_mfma<<<dim3(32, 32), blk, 0, stream>>>(qcb, qpb, kbb, vtb, rebb, attnb);

  gemm_mfma<<<g8, blk, 0, stream>>>(attnb, WcT, bc, nullptr, nullptr, x, nullptr,
                                    cpre, nullptr, MODE_F32RES);
  ln_kernel<<<8192, blk, 0, stream>>>(cpre, lnw, lnb, nullptr, ab16);
  gemm_mfma<<<g8, blk, 0, stream>>>(ab16, W1T, b1, nullptr, nullptr, nullptr, nullptr,
                                    h1b, nullptr, MODE_GELU);
  gemm_mfma<<<g8, blk, 0, stream>>>(h1b, W2T, b2, nullptr, nullptr, nullptr, ab16,
                                    h2pre, nullptr, MODE_F32RES);
  ln_kernel<<<8192, blk, 0, stream>>>(h2pre, lnw, lnb, outp, nullptr);
}

// Round 7
// 317.215 us; speedup vs baseline: 11.3536x; 1.2563x over previous
//
#include <hip/hip_runtime.h>
#include <math.h>

#define HDIM 512
#define LSEQ 2048
#define NH 8
#define DH 64
#define NEGBIG (-3.0e38f)

#define MODE_QDUAL  0
#define MODE_KV     1
#define MODE_VT     2
#define MODE_RE     3
#define MODE_F32RES 4
#define MODE_GELU   5

typedef short bf16x8 __attribute__((ext_vector_type(8)));
typedef float f32x4 __attribute__((ext_vector_type(4)));

__device__ __forceinline__ unsigned short f2b(float f) {
  union { float f; unsigned u; } x; x.f = f;
  unsigned r = x.u + 0x7FFF + ((x.u >> 16) & 1);
  return (unsigned short)(r >> 16);
}
__device__ __forceinline__ float b2f(unsigned short u) {
  union { unsigned u; float f; } x; x.u = ((unsigned)u) << 16;
  return x.f;
}

// async global->LDS, 16B per lane; LDS dest = wave-uniform base + lane*16
__device__ __forceinline__ void gl_lds16(const void* g, void* l) {
  __builtin_amdgcn_global_load_lds(
      (const __attribute__((address_space(1))) void*)g,
      (__attribute__((address_space(3))) void*)l, 16, 0, 0);
}

// ---------------------------------------------------------------------------
// fp32 -> bf16 vector convert (x, pos_enc)
// ---------------------------------------------------------------------------
__global__ __launch_bounds__(256) void conv_f32_bf16(
    const float* __restrict__ in, unsigned short* __restrict__ out, int n4)
{
  int idx = blockIdx.x * 256 + threadIdx.x;
  if (idx < n4) {
    float4 v = ((const float4*)in)[idx];
    ushort4 o; o.x = f2b(v.x); o.y = f2b(v.y); o.z = f2b(v.z); o.w = f2b(v.w);
    ((ushort4*)out)[idx] = o;
  }
}

// ---------------------------------------------------------------------------
// Weight prep: widx 0..3 (Wq,Wk,Wv,Wr [n,h,d] -> bf16 [n*64+d][h] B^T form),
//              widx 4..6 (Wc,W1,W2 [c,k] row-major -> bf16 straight convert)
// ---------------------------------------------------------------------------
__global__ __launch_bounds__(256) void conv_weights(
    const float* __restrict__ Wq, const float* __restrict__ Wk,
    const float* __restrict__ Wv, const float* __restrict__ Wr,
    const float* __restrict__ Wc, const float* __restrict__ W1,
    const float* __restrict__ W2, unsigned short* __restrict__ wT)
{
  const int widx = blockIdx.y;
  const float* src = (widx == 0) ? Wq : (widx == 1) ? Wk : (widx == 2) ? Wv :
                     (widx == 3) ? Wr : (widx == 4) ? Wc : (widx == 5) ? W1 : W2;
  unsigned short* dst = wT + (size_t)widx * 262144;
  const int t = threadIdx.x;
  const int tile = blockIdx.x;

  if (widx < 4) {
    __shared__ float td[64][65];
    const int h0 = (tile >> 3) * 64;
    const int n  = tile & 7;
    #pragma unroll
    for (int it = 0; it < 4; ++it) {
      int row = it * 16 + (t >> 4), dc = (t & 15) * 4;
      float4 v = *(const float4*)(src + (size_t)n * 32768 + (size_t)(h0 + row) * 64 + dc);
      td[row][dc] = v.x; td[row][dc + 1] = v.y; td[row][dc + 2] = v.z; td[row][dc + 3] = v.w;
    }
    __syncthreads();
    #pragma unroll
    for (int it = 0; it < 4; ++it) {
      int d = it * 16 + (t >> 4), h4 = (t & 15) * 4;
      ushort4 o;
      o.x = f2b(td[h4 + 0][d]); o.y = f2b(td[h4 + 1][d]);
      o.z = f2b(td[h4 + 2][d]); o.w = f2b(td[h4 + 3][d]);
      *(ushort4*)(dst + (size_t)(n * 64 + d) * 512 + h0 + h4) = o;
    }
  } else {
    #pragma unroll
    for (int i = 0; i < 4; ++i) {
      int f4 = tile * 1024 + i * 256 + t;
      float4 v = ((const float4*)src)[f4];
      ushort4 o; o.x = f2b(v.x); o.y = f2b(v.y); o.z = f2b(v.z); o.w = f2b(v.w);
      ((ushort4*)dst)[f4] = o;
    }
  }
}

// ---------------------------------------------------------------------------
// MFMA GEMM core (m97-style), 128x64 tile / block instance.
// 4 waves, each 64x32 (4x2 16x16x32 subtiles). BK=64 via global_load_lds(16B)
// into XOR-swizzled LDS. Epilogue via LDS roundtrip -> coalesced 16B stores.
// MODE_QDUAL additionally scales by 0.125 (attention 1/sqrt(D) folded in).
// ---------------------------------------------------------------------------
__device__ __forceinline__ void gemm_core(
    const unsigned short* __restrict__ A, const unsigned short* __restrict__ BT,
    const float* __restrict__ bias, const float* __restrict__ cb2,
    const float* __restrict__ pb2, const float* __restrict__ resf,
    const unsigned short* __restrict__ res16,
    void* __restrict__ C1v, unsigned short* __restrict__ C2, int mode,
    int bx, int by, char* SMEM)
{
  unsigned short* As = (unsigned short*)SMEM;            // [128][64] 16 KB
  unsigned short* Bs = (unsigned short*)(SMEM + 16384);  // [64][64]   8 KB

  const int t = threadIdx.x;
  const int w = t >> 6, lane = t & 63;
  const int l15 = lane & 15, quad = lane >> 4;
  const int r0 = by * 128;
  const int c0 = bx * 64;
  const int wm = (w >> 1) * 64, wc = (w & 1) * 32;

  f32x4 acc[4][2];
  #pragma unroll
  for (int sr = 0; sr < 4; ++sr)
    #pragma unroll
    for (int sc = 0; sc < 2; ++sc) acc[sr][sc] = (f32x4){0.f, 0.f, 0.f, 0.f};

  const int sub = lane >> 3;
  const int g   = (lane & 7) ^ sub;

  for (int k0 = 0; k0 < 512; k0 += 64) {
    __syncthreads();
    #pragma unroll
    for (int i = 0; i < 4; ++i) {
      int rowb = w * 32 + i * 8;
      gl_lds16(A + (size_t)(r0 + rowb + sub) * 512 + k0 + g * 8, As + rowb * 64);
    }
    #pragma unroll
    for (int i = 0; i < 2; ++i) {
      int rowb = w * 16 + i * 8;
      gl_lds16(BT + (size_t)(c0 + rowb + sub) * 512 + k0 + g * 8, Bs + rowb * 64);
    }
    __syncthreads();

    #pragma unroll
    for (int kk = 0; kk < 2; ++kk) {
      bf16x8 af[4], bf[2];
      #pragma unroll
      for (int s = 0; s < 4; ++s) {
        int ar = wm + s * 16 + l15;
        af[s] = *(const bf16x8*)(As + ar * 64 + (((quad + 4 * kk) ^ (ar & 7)) << 3));
      }
      #pragma unroll
      for (int s = 0; s < 2; ++s) {
        int br = wc + s * 16 + l15;
        bf[s] = *(const bf16x8*)(Bs + br * 64 + (((quad + 4 * kk) ^ (br & 7)) << 3));
      }
      #pragma unroll
      for (int sr = 0; sr < 4; ++sr)
        #pragma unroll
        for (int sc = 0; sc < 2; ++sc)
          acc[sr][sc] = __builtin_amdgcn_mfma_f32_16x16x32_bf16(
              af[sr], bf[sc], acc[sr][sc], 0, 0, 0);
    }
  }

  __syncthreads();

  unsigned short* C1u = (unsigned short*)C1v;
  float* C1f = (float*)C1v;

  if (mode == MODE_F32RES) {
    float* LDf = (float*)SMEM;                 // [64][68] per half
    #pragma unroll
    for (int h = 0; h < 2; ++h) {
      if ((w >> 1) == h) {
        #pragma unroll
        for (int sc = 0; sc < 2; ++sc) {
          int cl = wc + sc * 16 + l15;
          float bia = bias[c0 + cl];
          #pragma unroll
          for (int sr = 0; sr < 4; ++sr)
            #pragma unroll
            for (int r = 0; r < 4; ++r) {
              int ml = sr * 16 + quad * 4 + r;
              LDf[ml * 68 + cl] = acc[sr][sc][r] + bia;
            }
        }
      }
      __syncthreads();
      int row = t >> 2, m = r0 + h * 64 + row;
      #pragma unroll
      for (int j = 0; j < 4; ++j) {
        int col = (t & 3) * 16 + j * 4;
        float4 vv = *(const float4*)(LDf + row * 68 + col);
        size_t gofs = (size_t)m * 512 + c0 + col;
        if (resf) {
          float4 rr = *(const float4*)(resf + gofs);
          vv.x += rr.x; vv.y += rr.y; vv.z += rr.z; vv.w += rr.w;
        } else if (res16) {
          ushort4 rv = *(const ushort4*)(res16 + gofs);
          vv.x += b2f(rv.x); vv.y += b2f(rv.y); vv.z += b2f(rv.z); vv.w += b2f(rv.w);
        }
        *(float4*)(C1f + gofs) = vv;
      }
      __syncthreads();
    }
  } else if (mode == MODE_VT) {
    unsigned short* LDb = (unsigned short*)SMEM;   // [64][136]
    #pragma unroll
    for (int sc = 0; sc < 2; ++sc) {
      int cl = wc + sc * 16 + l15;
      float bia = bias[c0 + cl];
      #pragma unroll
      for (int sr = 0; sr < 4; ++sr)
        #pragma unroll
        for (int r = 0; r < 4; ++r) {
          int ml = wm + sr * 16 + quad * 4 + r;
          LDb[cl * 136 + ml] = f2b(acc[sr][sc][r] + bia);
        }
    }
    __syncthreads();
    int row = t >> 2;                 // c-local 0..63
    int c = c0 + row, n = c >> 6, d = c & 63;
    #pragma unroll
    for (int j = 0; j < 4; ++j) {
      int mcol = (t & 3) * 32 + j * 8;
      int4 val = *(const int4*)(LDb + row * 136 + mcol);
      int m = r0 + mcol, bb = m >> 11, l = m & 2047;
      *(int4*)(C1u + ((size_t)(bb * NH + n) * DH + d) * LSEQ + l) = val;
    }
  } else {
    unsigned short* LDb = (unsigned short*)SMEM;   // [128][72]
    const int passes = (mode == MODE_QDUAL) ? 2 : 1;
    for (int p = 0; p < passes; ++p) {
      #pragma unroll
      for (int sc = 0; sc < 2; ++sc) {
        int cl = wc + sc * 16 + l15;
        int c = c0 + cl;
        float bia = bias[c];
        float ex = (mode == MODE_QDUAL) ? ((p == 0) ? cb2[c] : pb2[c]) : 0.f;
        #pragma unroll
        for (int sr = 0; sr < 4; ++sr)
          #pragma unroll
          for (int r = 0; r < 4; ++r) {
            int ml = wm + sr * 16 + quad * 4 + r;
            float v = acc[sr][sc][r] + bia;
            if (mode == MODE_QDUAL) v = (v + ex) * 0.125f;   // fold 1/sqrt(D)
            if (mode == MODE_GELU)
              v = 0.5f * v * (1.0f + erff(v * 0.70710678118654752f));
            LDb[ml * 72 + cl] = f2b(v);
          }
      }
      __syncthreads();
      int row = t >> 1;
      #pragma unroll
      for (int j = 0; j < 4; ++j) {
        int col = (t & 1) * 32 + j * 8;
        int4 val = *(const int4*)(LDb + row * 72 + col);
        unsigned short* dst;
        int c = c0 + col, n = c >> 6, d = c & 63;
        if (mode == MODE_RE) {
          int m = r0 + row;
          dst = C1u + ((size_t)n * LSEQ + (LSEQ - 1 - m)) * DH + d;
        } else if (mode == MODE_GELU) {
          dst = C1u + (size_t)(r0 + row) * 512 + c0 + col;
        } else { // QDUAL / KV
          int m = r0 + row, bb = m >> 11, l = m & 2047;
          dst = ((p == 0) ? C1u : C2) + ((size_t)(bb * NH + n) * LSEQ + l) * DH + d;
        }
        *(int4*)dst = val;
      }
      if (p + 1 < passes) __syncthreads();
    }
  }
}

__global__ __launch_bounds__(256) void gemm_mfma(
    const unsigned short* __restrict__ A, const unsigned short* __restrict__ BT,
    const float* __restrict__ bias, const float* __restrict__ resf,
    const unsigned short* __restrict__ res16,
    void* __restrict__ C1v, int mode)
{
  __shared__ __align__(16) char SMEM[24576];
  gemm_core(A, BT, bias, nullptr, nullptr, resf, res16, C1v, nullptr, mode,
            blockIdx.x, blockIdx.y, SMEM);
}

// Fused Q/K/V/RE projections: blockIdx.z selects the GEMM.
__global__ __launch_bounds__(256) void qkv_fused(
    const unsigned short* __restrict__ xb, const unsigned short* __restrict__ posb,
    const unsigned short* __restrict__ WqT, const unsigned short* __restrict__ WkT,
    const unsigned short* __restrict__ WvT, const unsigned short* __restrict__ WrT,
    const float* __restrict__ bq, const float* __restrict__ bk,
    const float* __restrict__ bv, const float* __restrict__ br,
    const float* __restrict__ cbv, const float* __restrict__ pbv,
    unsigned short* __restrict__ qcb, unsigned short* __restrict__ qpb,
    unsigned short* __restrict__ kbb, unsigned short* __restrict__ vtb,
    unsigned short* __restrict__ rebb)
{
  __shared__ __align__(16) char SMEM[24576];
  const int z = blockIdx.z;
  if (z == 0) {
    gemm_core(xb, WqT, bq, cbv, pbv, nullptr, nullptr, qcb, qpb, MODE_QDUAL,
              blockIdx.x, blockIdx.y, SMEM);
  } else if (z == 1) {
    gemm_core(xb, WkT, bk, nullptr, nullptr, nullptr, nullptr, kbb, nullptr, MODE_KV,
              blockIdx.x, blockIdx.y, SMEM);
  } else if (z == 2) {
    gemm_core(xb, WvT, bv, nullptr, nullptr, nullptr, nullptr, vtb, nullptr, MODE_VT,
              blockIdx.x, blockIdx.y, SMEM);
  } else {
    if (blockIdx.y >= 16) return;
    gemm_core(posb, WrT, br, nullptr, nullptr, nullptr, nullptr, rebb, nullptr, MODE_RE,
              blockIdx.x, blockIdx.y, SMEM);
  }
}

// ---------------------------------------------------------------------------
// MFMA flash attention, Transformer-XL relative positions.
// R7: shuffle-free T/P packing (direct ds_write_u16; P uses quad-staggered
// row layout PROW(i)=i*72+(i>>2)*8 -> 16B-aligned b128 reads, 2-way banking).
// Max-free softmax (scores pre-scaled 0.125 in q-projection). 47.6 KB LDS.
// ---------------------------------------------------------------------------
#define PROW(i) ((i) * 72 + (((i) >> 2) << 3))

__global__ __launch_bounds__(256, 3) void attn_mfma(
    const unsigned short* __restrict__ qcb, const unsigned short* __restrict__ qpb,
    const unsigned short* __restrict__ kbb, const unsigned short* __restrict__ vtb,
    const unsigned short* __restrict__ rebb, unsigned short* __restrict__ outb)
{
  __shared__ __align__(16) unsigned short Ks[64 * 72];
  __shared__ __align__(16) unsigned short Vts[64 * 72];
  __shared__ __align__(16) unsigned short Res[128 * 72];
  __shared__ __align__(16) unsigned short TPb[4 * 16 * 84];   // T(84) / P(staggered 72) aliased

  const int t = threadIdx.x;
  const int bn = blockIdx.x;
  const int b = bn >> 3, n = bn & 7;
  const int ib = 31 - blockIdx.y;       // heavy blocks dispatched first
  const int i0 = ib * 64;
  const int w = t >> 6;
  const int lane = t & 63;
  const int l15 = lane & 15, quad = lane >> 4;

  bf16x8 qcf[2], qpf[2];
  {
    size_t base = ((size_t)bn * LSEQ + i0 + 16 * w + l15) * DH + quad * 8;
    qcf[0] = *(const bf16x8*)(qcb + base);
    qcf[1] = *(const bf16x8*)(qcb + base + 32);
    qpf[0] = *(const bf16x8*)(qpb + base);
    qpf[1] = *(const bf16x8*)(qpb + base + 32);
  }

  f32x4 Of[4];
  #pragma unroll
  for (int s = 0; s < 4; ++s) Of[s] = (f32x4){0.f, 0.f, 0.f, 0.f};
  float lsum[4] = {0.f, 0.f, 0.f, 0.f};

  unsigned short* Tw = TPb + w * 1344;
  const int Ibase = i0 + 16 * w;
  const int nt = ib + 1;

  const int r2 = t >> 2, gl2 = t & 3;
  const int r1 = t >> 1, h1 = t & 1;

  for (int tt = 0; tt < nt; ++tt) {
    const int j0 = tt * 64;
    const int db = i0 - j0;

    // ---- prefetch K/V/Res into registers (overlaps other waves' compute) ----
    const int4* skp = (const int4*)(kbb + ((size_t)bn * LSEQ + j0 + r2) * DH + gl2 * 16);
    int4 ka0 = skp[0], ka1 = skp[1];
    const int4* svp = (const int4*)(vtb + ((size_t)bn * DH + r2) * LSEQ + j0 + gl2 * 16);
    int4 va0 = svp[0], va1 = svp[1];
    int dist = db - 63 + r1;
    int4 ra[2][2];
    #pragma unroll
    for (int gi = 0; gi < 2; ++gi) {
      if (dist >= 0 && dist < LSEQ) {
        const int4* srp = (const int4*)(rebb + ((size_t)n * LSEQ + dist) * DH + (h1 * 2 + gi) * 16);
        ra[gi][0] = srp[0]; ra[gi][1] = srp[1];
      } else {
        int4 z = {0, 0, 0, 0};
        ra[gi][0] = z; ra[gi][1] = z;
      }
    }
    __syncthreads();   // previous tile's LDS reads complete
    {
      unsigned short* dk = Ks + r2 * 72 + ((gl2 ^ (r2 & 3)) * 16);
      *(int4*)(dk) = ka0; *(int4*)(dk + 8) = ka1;
      unsigned short* dv = Vts + r2 * 72 + ((gl2 ^ (r2 & 3)) * 16);
      *(int4*)(dv) = va0; *(int4*)(dv + 8) = va1;
      #pragma unroll
      for (int gi = 0; gi < 2; ++gi) {
        int gl = h1 * 2 + gi;
        unsigned short* dr = Res + r1 * 72 + ((gl ^ (r1 & 3)) * 16);
        *(int4*)(dr) = ra[gi][0]; *(int4*)(dr + 8) = ra[gi][1];
      }
    }
    __syncthreads();

    // ---- content scores ----
    f32x4 Sf[4];
    #pragma unroll
    for (int s = 0; s < 4; ++s) {
      f32x4 acc = {0.f, 0.f, 0.f, 0.f};
      int row = 16 * s + l15;
      #pragma unroll
      for (int kk = 0; kk < 2; ++kk) {
        int g = (quad >> 1) + 2 * kk;
        bf16x8 bfr = *(const bf16x8*)(Ks + row * 72 + ((g ^ (row & 3)) * 16) + (quad & 1) * 8);
        acc = __builtin_amdgcn_mfma_f32_16x16x32_bf16(qcf[kk], bfr, acc, 0, 0, 0);
      }
      Sf[s] = acc;
    }
    // ---- positional T = qp . re_band^T -> Tw (direct u16 writes) ----
    #pragma unroll
    for (int s = 0; s < 5; ++s) {
      f32x4 acc = {0.f, 0.f, 0.f, 0.f};
      int row = 16 * w + 16 * s + l15;
      #pragma unroll
      for (int kk = 0; kk < 2; ++kk) {
        int g = (quad >> 1) + 2 * kk;
        bf16x8 bfr = *(const bf16x8*)(Res + row * 72 + ((g ^ (row & 3)) * 16) + (quad & 1) * 8);
        acc = __builtin_amdgcn_mfma_f32_16x16x32_bf16(qpf[kk], bfr, acc, 0, 0, 0);
      }
      #pragma unroll
      for (int r = 0; r < 4; ++r) {
        int i = quad * 4 + r;
        Tw[i * 84 + 16 * s + l15] = f2b(acc[r]);
      }
    }
    asm volatile("s_waitcnt lgkmcnt(0)" ::: "memory");

    // ---- max-free softmax ----
    float p_s[4][4];
    #pragma unroll
    for (int s = 0; s < 4; ++s)
      #pragma unroll
      for (int r = 0; r < 4; ++r) {
        int i = quad * 4 + r;
        float tval = b2f(Tw[i * 84 + 63 + i - 16 * s - l15]);
        float v = Sf[s][r] + tval;
        int j = j0 + 16 * s + l15;
        float p = (j <= Ibase + i) ? __expf(v) : 0.0f;
        p_s[s][r] = p;
        lsum[r] += p;
      }
    // pack P (direct u16 writes, quad-staggered rows)
    #pragma unroll
    for (int s = 0; s < 4; ++s)
      #pragma unroll
      for (int r = 0; r < 4; ++r) {
        int i = quad * 4 + r;
        Tw[PROW(i) + ((s ^ (i & 3)) * 16) + l15] = f2b(p_s[s][r]);
      }
    asm volatile("s_waitcnt lgkmcnt(0)" ::: "memory");

    // ---- PV: O += P . V ----
    #pragma unroll
    for (int kk = 0; kk < 2; ++kk) {
      int g = (quad >> 1) + 2 * kk;
      bf16x8 pa = *(const bf16x8*)(Tw + PROW(l15) + ((g ^ (l15 & 3)) * 16) + (quad & 1) * 8);
      #pragma unroll
      for (int s = 0; s < 4; ++s) {
        int d = 16 * s + l15;
        bf16x8 vb8 = *(const bf16x8*)(Vts + d * 72 + ((g ^ (d & 3)) * 16) + (quad & 1) * 8);
        Of[s] = __builtin_amdgcn_mfma_f32_16x16x32_bf16(pa, vb8, Of[s], 0, 0, 0);
      }
    }
  }

  // ---- epilogue: reduce l across the 16-lane row group, write bf16 ----
  #pragma unroll
  for (int r = 0; r < 4; ++r) {
    float rs = lsum[r];
    rs += __shfl_xor(rs, 1, 64);
    rs += __shfl_xor(rs, 2, 64);
    rs += __shfl_xor(rs, 4, 64);
    rs += __shfl_xor(rs, 8, 64);
    float linv = 1.0f / rs;
    int I = Ibase + quad * 4 + r;
    size_t base = ((size_t)b * LSEQ + I) * HDIM + n * DH;
    #pragma unroll
    for (int s = 0; s < 4; ++s)
      outb[base + 16 * s + l15] = f2b(Of[s][r] * linv);
  }
}

// ---------------------------------------------------------------------------
// LayerNorm over last dim (512): outf (fp32) and/or out16 (bf16), nullable
// ---------------------------------------------------------------------------
__global__ __launch_bounds__(256) void ln_kernel(
    const float* __restrict__ xin, const float* __restrict__ w,
    const float* __restrict__ bb, float* __restrict__ outf,
    unsigned short* __restrict__ out16)
{
  __shared__ float red[8];
  const int row = blockIdx.x, t = threadIdx.x;
  const size_t base = (size_t)row * 512;
  float v0 = xin[base + t], v1 = xin[base + t + 256];
  float s = v0 + v1;
  #pragma unroll
  for (int off = 32; off >= 1; off >>= 1) s += __shfl_xor(s, off, 64);
  if ((t & 63) == 0) red[t >> 6] = s;
  __syncthreads();
  float mean = (red[0] + red[1] + red[2] + red[3]) * (1.0f / 512.0f);
  float d0 = v0 - mean, d1 = v1 - mean;
  float s2 = d0 * d0 + d1 * d1;
  #pragma unroll
  for (int off = 32; off >= 1; off >>= 1) s2 += __shfl_xor(s2, off, 64);
  if ((t & 63) == 0) red[4 + (t >> 6)] = s2;
  __syncthreads();
  float var = (red[4] + red[5] + red[6] + red[7]) * (1.0f / 512.0f);
  float inv = 1.0f / sqrtf(var + 1e-12f);
  float o0 = w[t] * d0 * inv + bb[t];
  float o1 = w[t + 256] * d1 * inv + bb[t + 256];
  if (outf)  { outf[base + t] = o0; outf[base + t + 256] = o1; }
  if (out16) { out16[base + t] = f2b(o0); out16[base + t + 256] = f2b(o1); }
}

// ---------------------------------------------------------------------------
extern "C" void kernel_launch(void* const* d_in, const int* in_sizes, int n_in,
                              void* d_out, int out_size, void* d_ws, size_t ws_size,
                              hipStream_t stream)
{
  (void)in_sizes; (void)n_in; (void)out_size; (void)ws_size;
  const float* x   = (const float*)d_in[0];
  const float* pos = (const float*)d_in[1];
  const float* Wq  = (const float*)d_in[2];
  const float* bq  = (const float*)d_in[3];
  const float* Wk  = (const float*)d_in[4];
  const float* bk  = (const float*)d_in[5];
  const float* Wv  = (const float*)d_in[6];
  const float* bv  = (const float*)d_in[7];
  const float* Wr  = (const float*)d_in[8];
  const float* br  = (const float*)d_in[9];
  const float* cbv = (const float*)d_in[10];
  const float* pbv = (const float*)d_in[11];
  const float* Wc  = (const float*)d_in[12];
  const float* bc  = (const float*)d_in[13];
  const float* W1  = (const float*)d_in[14];
  const float* b1  = (const float*)d_in[15];
  const float* W2  = (const float*)d_in[16];
  const float* b2  = (const float*)d_in[17];
  const float* lnw = (const float*)d_in[18];
  const float* lnb = (const float*)d_in[19];
  char* ws = (char*)d_ws;
  float* outp = (float*)d_out;

  unsigned short* xb   = (unsigned short*)(ws);
  unsigned short* posb = (unsigned short*)(ws + 8388608);
  unsigned short* wT   = (unsigned short*)(ws + 10485760);
  unsigned short* qcb  = (unsigned short*)(ws + 14155776);
  unsigned short* qpb  = (unsigned short*)(ws + 22544384);
  unsigned short* kbb  = (unsigned short*)(ws + 30932992);
  unsigned short* vtb  = (unsigned short*)(ws + 39321600);
  unsigned short* rebb = (unsigned short*)(ws + 47710208);
  unsigned short* WqT = wT;
  unsigned short* WkT = wT + 262144;
  unsigned short* WvT = wT + 2 * 262144;
  unsigned short* WrT = wT + 3 * 262144;
  unsigned short* WcT = wT + 4 * 262144;
  unsigned short* W1T = wT + 5 * 262144;
  unsigned short* W2T = wT + 6 * 262144;
  unsigned short* attnb = (unsigned short*)d_out;
  float*          cpre  = (float*)(ws + 14155776);
  unsigned short* ab16  = (unsigned short*)(ws);
  unsigned short* h1b   = (unsigned short*)(ws + 30932992);
  float*          h2pre = (float*)(ws + 14155776);

  dim3 blk(256);
  dim3 g8(8, 64);    // M=8192: 128x64 tiles -> 512 blocks

  conv_f32_bf16<<<4096, blk, 0, stream>>>(x, xb, 1048576);
  conv_f32_bf16<<<1024, blk, 0, stream>>>(pos, posb, 262144);
  conv_weights<<<dim3(64, 7), blk, 0, stream>>>(Wq, Wk, Wv, Wr, Wc, W1, W2, wT);

  qkv_fused<<<dim3(8, 64, 4), blk, 0, stream>>>(
      xb, posb, WqT, WkT, WvT, WrT, bq, bk, bv, br, cbv, pbv,
      qcb, qpb, kbb, vtb, rebb);

  attn_mfma<<<dim3(32, 32), blk, 0, stream>>>(qcb, qpb, kbb, vtb, rebb, attnb);

  gemm_mfma<<<g8, blk, 0, stream>>>(attnb, WcT, bc, x, nullptr, cpre, MODE_F32RES);
  ln_kernel<<<8192, blk, 0, stream>>>(cpre, lnw, lnb, nullptr, ab16);
  gemm_mfma<<<g8, blk, 0, stream>>>(ab16, W1T, b1, nullptr, nullptr, h1b, MODE_GELU);
  gemm_mfma<<<g8, blk, 0, stream>>>(h1b, W2T, b2, nullptr, ab16, h2pre, MODE_F32RES);
  ln_kernel<<<8192, blk, 0, stream>>>(h2pre, lnw, lnb, outp, nullptr);
}